// Round 4
// baseline (68238.202 us; speedup 1.0000x reference)
//
#include <hip/hip_runtime.h>
#include <cstdint>
#include <cstddef>

#define BB   16
#define SS   256
#define IND  128
#define OUTD 256
#define HCC  256
#define G4   1024   // 4*HC
#define ZD   384    // IND + H*M
#define NN   128    // memory units
#define MM   64     // memory dim
#define HH   4      // heads
#define MLD  65     // padded mem row

struct Params {
  const int*   x;
  const float* emb;
  const float* mem0;
  const float* wih; int wih_sI, wih_sK;   // element(i,k) = wih[i*sI + k*sK]
  const float* whh; int whh_sI, whh_sK;
  const float* b_ih; const float* b_hh;
  const float* rk_W; const float* rk_b;
  const float* rb_W; const float* rb_b;
  const float* rg_W; const float* rg_b;
  const float* rs_W; const float* rs_b;
  const float* rgm_W; const float* rgm_b;
  const float* wk_W; const float* wk_b;
  const float* wb_W; const float* wb_b;
  const float* wg_W; const float* wg_b;
  const float* ws_W; const float* ws_b;
  const float* wgm_W; const float* wgm_b;
  const float* er_W; const float* er_b;
  const float* ad_W; const float* ad_b;
  const float* outW; int outW_sK, outW_sO; // element(k,o) = outW[k*sK + o*sO], k<512
  const float* out_b;
  float* out;
};

__device__ __forceinline__ double dsigm(double x) { return 1.0 / (1.0 + exp(-x)); }
__device__ __forceinline__ double dsoftplus(double x) {
  // numerically stable softplus, matches log1p(exp(x)) semantics in fp64
  return (x > 0.0) ? x + log1p(exp(-x)) : log1p(exp(x));
}

// ---------- prep: tiled transpose dst[C][R] = src[R][C]^T (fp32) ----------
__global__ __launch_bounds__(256) void transpose_k(const float* __restrict__ src,
                                                   float* __restrict__ dst,
                                                   int R, int C) {
  __shared__ float tile[32][33];
  const int bx = blockIdx.x * 32;  // over C
  const int by = blockIdx.y * 32;  // over R
  const int tx = threadIdx.x, ty = threadIdx.y; // 32x8
  for (int i = ty; i < 32; i += 8) {
    int r = by + i, c = bx + tx;
    if (r < R && c < C) tile[i][tx] = src[(size_t)r * C + c];
  }
  __syncthreads();
  for (int i = ty; i < 32; i += 8) {
    int c = bx + i, r = by + tx;
    if (c < C && r < R) dst[(size_t)c * R + r] = tile[tx][i];
  }
}

// ---------- main persistent NTM kernel: one block per batch element ----------
// All recurrent state & arithmetic in fp64 to track the fp64 numpy reference.
__global__ __launch_bounds__(1024) void ntm_main(Params p) {
  __shared__ double mem[NN][MLD];                      // 66.5 KB
  __shared__ double h_s[HCC];
  __shared__ double c_s[HCC];
  __shared__ double z_s[ZD];
  __shared__ double gates_s[G4];
  __shared__ double rv_s[HH * MM];
  __shared__ double rw_s[HH][NN];
  __shared__ double ww_s[HH][NN];
  __shared__ double rk_s[HH][MM];
  __shared__ double wk_s[HH][MM];
  __shared__ double ev_s[HH][MM];
  __shared__ double av_s[HH][MM];
  __shared__ double scal_s[6][HH];                     // rb,rg,rgm,wb,wg,wgm (activated)
  __shared__ double shift_s[2][HH][3];                 // raw shift logits (r,w)
  __shared__ double memnorm[NN];
  __shared__ double wavescr[8][NN];
  __shared__ double part_s[6][OUTD];

  const int b = blockIdx.x;
  const int tid = threadIdx.x;

  // ---- init state ----
  for (int i = tid; i < NN * MM; i += 1024) mem[i >> 6][i & 63] = (double)p.mem0[i];
  if (tid < HCC) { h_s[tid] = 0.0; c_s[tid] = 0.0; }
  if (tid < HH * NN) { rw_s[tid >> 7][tid & 127] = 0.0; ww_s[tid >> 7][tid & 127] = 0.0; }
  if (tid < HH * MM) rv_s[tid] = 0.0;
  __syncthreads();

  for (int t = 0; t < SS; ++t) {
    // ---- P0: memory row norms + build z = [emb(x_t), rv] ----
    if (tid < NN) {
      double s = 0.0;
      #pragma unroll 8
      for (int m = 0; m < MM; ++m) { double v = mem[tid][m]; s += v * v; }
      memnorm[tid] = fmax(sqrt(s), 1e-12);
    } else if (tid < NN + ZD) {
      int k = tid - NN;
      if (k < IND) {
        int xbt = p.x[b * SS + t];
        z_s[k] = (double)p.emb[(size_t)xbt * IND + k];
      } else {
        z_s[k] = rv_s[k - IND];
      }
    }
    __syncthreads();

    // ---- P1: gates[i] = W_ih z + W_hh h + b  (each thread one of 1024 outputs) ----
    {
      const int i = tid;
      double acc = (double)p.b_ih[i] + (double)p.b_hh[i];
      {
        const float* wp = p.wih + (size_t)i * p.wih_sI;
        const int sK = p.wih_sK;
        #pragma unroll 4
        for (int j = 0; j < ZD / 4; ++j) {
          const float* w4 = wp + (size_t)(4 * j) * sK;
          acc += (double)w4[0]      * z_s[4 * j]
               + (double)w4[sK]     * z_s[4 * j + 1]
               + (double)w4[2 * sK] * z_s[4 * j + 2]
               + (double)w4[3 * sK] * z_s[4 * j + 3];
        }
      }
      {
        const float* wp = p.whh + (size_t)i * p.whh_sI;
        const int sK = p.whh_sK;
        #pragma unroll 4
        for (int j = 0; j < HCC / 4; ++j) {
          const float* w4 = wp + (size_t)(4 * j) * sK;
          acc += (double)w4[0]      * h_s[4 * j]
               + (double)w4[sK]     * h_s[4 * j + 1]
               + (double)w4[2 * sK] * h_s[4 * j + 2]
               + (double)w4[3 * sK] * h_s[4 * j + 3];
        }
      }
      gates_s[i] = acc;
    }
    __syncthreads();

    // ---- P2: LSTM cell update (torch gate order i,f,g,o) ----
    if (tid < HCC) {
      double gi = gates_s[tid], gf = gates_s[HCC + tid];
      double gg = gates_s[2 * HCC + tid], go = gates_s[3 * HCC + tid];
      double cn = dsigm(gf) * c_s[tid] + dsigm(gi) * tanh(gg);
      c_s[tid] = cn;
      h_s[tid] = dsigm(go) * tanh(cn);
    }
    __syncthreads();

    // ---- P3: head linears (vec: rk,wk,er->ev,ad->av; scalars: b,g,gm,shift) ----
    {
      const int a = tid >> 8, idx = tid & 255, hh = idx >> 6, m = idx & 63;
      const float* W; const float* bb;
      if (a == 0)      { W = p.rk_W; bb = p.rk_b; }
      else if (a == 1) { W = p.wk_W; bb = p.wk_b; }
      else if (a == 2) { W = p.er_W; bb = p.er_b; }
      else             { W = p.ad_W; bb = p.ad_b; }
      const float* Wp = W + (size_t)(hh * HCC) * MM + m;
      double acc = (double)bb[hh * MM + m];
      #pragma unroll 4
      for (int j = 0; j < HCC / 4; ++j) {
        const float* w4 = Wp + (size_t)(4 * j) * MM;
        acc += (double)w4[0]      * h_s[4 * j]
             + (double)w4[MM]     * h_s[4 * j + 1]
             + (double)w4[2 * MM] * h_s[4 * j + 2]
             + (double)w4[3 * MM] * h_s[4 * j + 3];
      }
      if (a == 0)      rk_s[hh][m] = acc;
      else if (a == 1) wk_s[hh][m] = acc;
      else if (a == 2) ev_s[hh][m] = dsigm(acc);
      else             av_s[hh][m] = tanh(acc);

      if (tid < 48) {
        if (tid < 24) {
          int pp = tid >> 2, h2 = tid & 3;
          const float* W2; const float* b2;
          switch (pp) {
            case 0:  W2 = p.rb_W;  b2 = p.rb_b;  break;
            case 1:  W2 = p.rg_W;  b2 = p.rg_b;  break;
            case 2:  W2 = p.rgm_W; b2 = p.rgm_b; break;
            case 3:  W2 = p.wb_W;  b2 = p.wb_b;  break;
            case 4:  W2 = p.wg_W;  b2 = p.wg_b;  break;
            default: W2 = p.wgm_W; b2 = p.wgm_b; break;
          }
          double acc2 = (double)b2[h2];
          const float* w2 = W2 + (size_t)h2 * HCC;
          #pragma unroll 4
          for (int c = 0; c < HCC; ++c) acc2 += h_s[c] * (double)w2[c];
          double r;
          if (pp == 1 || pp == 4) r = dsigm(acc2);
          else { r = dsoftplus(acc2); if (pp == 2 || pp == 5) r += 1.0; }
          scal_s[pp][h2] = r;
        } else {
          int q = tid - 24, pre = q / 12, rr = q % 12, h2 = rr / 3, j = rr % 3;
          const float* W2 = pre ? p.ws_W : p.rs_W;
          const float* b2 = pre ? p.ws_b : p.rs_b;
          double acc2 = (double)b2[h2 * 3 + j];
          const float* w2 = W2 + (size_t)(h2 * HCC) * 3 + j;
          #pragma unroll 4
          for (int c = 0; c < HCC; ++c) acc2 += h_s[c] * (double)w2[(size_t)c * 3];
          shift_s[pre][h2][j] = acc2;
        }
      }
    }
    __syncthreads();

    // ---- P4: addressing (waves 0..7 = {read,write} x 4 heads); waves 8..15: out h-part ----
    {
      const int w = tid >> 6, l = tid & 63;
      if (w < 8) {
        const int isW = w >> 2, hh = w & 3;
        const double* kv = isW ? wk_s[hh] : rk_s[hh];
        double* prevw = isW ? ww_s[hh] : rw_s[hh];
        const double beta  = scal_s[isW ? 3 : 0][hh];
        const double g     = scal_s[isW ? 4 : 1][hh];
        const double gamma = scal_s[isW ? 5 : 2][hh];
        // ||k||
        double kl = kv[l];
        double kn2 = kl * kl;
        #pragma unroll
        for (int d = 1; d < 64; d <<= 1) kn2 += __shfl_xor(kn2, d, 64);
        const double kn = fmax(sqrt(kn2), 1e-12);
        // cosine sim * beta for rows n=l and n=l+64
        double s0 = 0.0, s1 = 0.0;
        #pragma unroll 4
        for (int m = 0; m < MM; ++m) {
          double km = kv[m];
          s0 += mem[l][m] * km;
          s1 += mem[l + 64][m] * km;
        }
        double v0 = beta * (s0 / (memnorm[l] * kn));
        double v1 = beta * (s1 / (memnorm[l + 64] * kn));
        // softmax over 128
        double mx = fmax(v0, v1);
        #pragma unroll
        for (int d = 1; d < 64; d <<= 1) mx = fmax(mx, __shfl_xor(mx, d, 64));
        double e0 = exp(v0 - mx), e1 = exp(v1 - mx);
        double sm = e0 + e1;
        #pragma unroll
        for (int d = 1; d < 64; d <<= 1) sm += __shfl_xor(sm, d, 64);
        const double inv = 1.0 / sm;
        // interpolation gate
        double wg0 = g * (e0 * inv) + (1.0 - g) * prevw[l];
        double wg1 = g * (e1 * inv) + (1.0 - g) * prevw[l + 64];
        wavescr[w][l] = wg0;
        wavescr[w][l + 64] = wg1;
        // shift softmax (3)
        double sh0 = shift_s[isW][hh][0], sh1 = shift_s[isW][hh][1], sh2 = shift_s[isW][hh][2];
        double shm = fmax(sh0, fmax(sh1, sh2));
        double es0 = exp(sh0 - shm), es1 = exp(sh1 - shm), es2 = exp(sh2 - shm);
        double esum = es0 + es1 + es2;
        es0 /= esum; es1 /= esum; es2 /= esum;
        // circular conv: w_[n] = s0*wg[n+1] + s1*wg[n] + s2*wg[n-1]  (mod 128)
        double w_0 = es0 * wavescr[w][(l + 1) & 127] + es1 * wavescr[w][l]
                   + es2 * wavescr[w][(l + 127) & 127];
        const int n1 = l + 64;
        double w_1 = es0 * wavescr[w][(n1 + 1) & 127] + es1 * wavescr[w][n1]
                   + es2 * wavescr[w][(n1 + 127) & 127];   // FIXED: was (n1+63)&127
        // sharpen + renormalize
        double p0 = pow(w_0, gamma), p1 = pow(w_1, gamma);
        double tot = p0 + p1;
        #pragma unroll
        for (int d = 1; d < 64; d <<= 1) tot += __shfl_xor(tot, d, 64);
        const double invt = 1.0 / tot;
        prevw[l] = p0 * invt;
        prevw[l + 64] = p1 * invt;
      } else {
        // logits partials for the h half (k = 0..255)
        const int o = tid & 255, hf = (tid - 512) >> 8;  // hf in {0,1}
        const float* Wp = p.outW + (size_t)o * p.outW_sO + (size_t)(hf * 128) * p.outW_sK;
        const int sK = p.outW_sK;
        double acc = 0.0;
        const double* hp = h_s + hf * 128;
        #pragma unroll 4
        for (int k = 0; k < 128; ++k) acc += hp[k] * (double)Wp[(size_t)k * sK];
        part_s[hf][o] = acc;
      }
    }
    __syncthreads();

    // ---- P5: read vector rv[h][m] = sum_n rw[h][n] * mem[n][m] (OLD mem) ----
    if (tid < HH * MM) {
      const int hh = tid >> 6, m = tid & 63;
      double acc = 0.0;
      #pragma unroll 4
      for (int n = 0; n < NN; ++n) acc += rw_s[hh][n] * mem[n][m];
      rv_s[tid] = acc;
    }
    __syncthreads();

    // ---- P6: memory write (erase+add) + logits partials for rv half ----
    {
      const int n = tid >> 3, j = tid & 7, m0 = j * 8;
      const double w0 = ww_s[0][n], w1 = ww_s[1][n], w2 = ww_s[2][n], w3 = ww_s[3][n];
      #pragma unroll
      for (int m = m0; m < m0 + 8; ++m) {
        double e  = w0 * ev_s[0][m] + w1 * ev_s[1][m] + w2 * ev_s[2][m] + w3 * ev_s[3][m];
        double aa = w0 * av_s[0][m] + w1 * av_s[1][m] + w2 * av_s[2][m] + w3 * av_s[3][m];
        mem[n][m] = mem[n][m] * (1.0 - e) + aa;
      }
      const int o = tid & 255, hf = tid >> 8;  // hf in 0..3
      const float* Wp = p.outW + (size_t)o * p.outW_sO + (size_t)(HCC + hf * 64) * p.outW_sK;
      const int sK = p.outW_sK;
      double acc = 0.0;
      const double* rvp = rv_s + hf * 64;
      #pragma unroll 4
      for (int k = 0; k < 64; ++k) acc += rvp[k] * (double)Wp[(size_t)k * sK];
      part_s[2 + hf][o] = acc;
    }
    __syncthreads();

    // ---- P7: logits = sum(partials) + bias -> global ----
    if (tid < OUTD) {
      double r = part_s[0][tid] + part_s[1][tid] + part_s[2][tid]
               + part_s[3][tid] + part_s[4][tid] + part_s[5][tid] + (double)p.out_b[tid];
      p.out[((size_t)b * SS + t) * OUTD + tid] = (float)r;
    }
    __syncthreads();
  }
}

extern "C" void kernel_launch(void* const* d_in, const int* in_sizes, int n_in,
                              void* d_out, int out_size, void* d_ws, size_t ws_size,
                              hipStream_t stream) {
  const int*   x     = (const int*)d_in[0];
  const float* emb   = (const float*)d_in[1];
  const float* mem0  = (const float*)d_in[2];
  const float* w_ih  = (const float*)d_in[3];
  const float* w_hh  = (const float*)d_in[4];
  const float* b_ih  = (const float*)d_in[5];
  const float* b_hh  = (const float*)d_in[6];
  const float* rk_W  = (const float*)d_in[7];
  const float* rk_b  = (const float*)d_in[8];
  const float* rb_W  = (const float*)d_in[9];
  const float* rb_b  = (const float*)d_in[10];
  const float* rg_W  = (const float*)d_in[11];
  const float* rg_b  = (const float*)d_in[12];
  const float* rs_W  = (const float*)d_in[13];
  const float* rs_b  = (const float*)d_in[14];
  const float* rgm_W = (const float*)d_in[15];
  const float* rgm_b = (const float*)d_in[16];
  const float* wk_W  = (const float*)d_in[17];
  const float* wk_b  = (const float*)d_in[18];
  const float* wb_W  = (const float*)d_in[19];
  const float* wb_b  = (const float*)d_in[20];
  const float* wg_W  = (const float*)d_in[21];
  const float* wg_b  = (const float*)d_in[22];
  const float* ws_W  = (const float*)d_in[23];
  const float* ws_b  = (const float*)d_in[24];
  const float* wgm_W = (const float*)d_in[25];
  const float* wgm_b = (const float*)d_in[26];
  const float* er_W  = (const float*)d_in[27];
  const float* er_b  = (const float*)d_in[28];
  const float* ad_W  = (const float*)d_in[29];
  const float* ad_b  = (const float*)d_in[30];
  const float* out_W = (const float*)d_in[31];
  const float* out_b = (const float*)d_in[32];
  float* out = (float*)d_out;

  Params p{};
  p.x = x; p.emb = emb; p.mem0 = mem0;
  p.b_ih = b_ih; p.b_hh = b_hh;
  p.rk_W = rk_W; p.rk_b = rk_b; p.rb_W = rb_W; p.rb_b = rb_b;
  p.rg_W = rg_W; p.rg_b = rg_b; p.rs_W = rs_W; p.rs_b = rs_b;
  p.rgm_W = rgm_W; p.rgm_b = rgm_b;
  p.wk_W = wk_W; p.wk_b = wk_b; p.wb_W = wb_W; p.wb_b = wb_b;
  p.wg_W = wg_W; p.wg_b = wg_b; p.ws_W = ws_W; p.ws_b = ws_b;
  p.wgm_W = wgm_W; p.wgm_b = wgm_b;
  p.er_W = er_W; p.er_b = er_b; p.ad_W = ad_W; p.ad_b = ad_b;
  p.out_b = out_b; p.out = out;

  const size_t nWih = (size_t)ZD * G4;      // 393216
  const size_t nWhh = (size_t)HCC * G4;     // 262144
  const size_t nWout = (size_t)512 * OUTD;  // 131072
  const size_t needT = (nWih + nWhh + nWout) * sizeof(float);
  float* ws = (float*)d_ws;

  if (ws_size >= needT) {
    dim3 blk(32, 8);
    transpose_k<<<dim3(ZD / 32, G4 / 32), blk, 0, stream>>>(w_ih, ws, G4, ZD);
    transpose_k<<<dim3(HCC / 32, G4 / 32), blk, 0, stream>>>(w_hh, ws + nWih, G4, HCC);
    transpose_k<<<dim3(512 / 32, OUTD / 32), blk, 0, stream>>>(out_W, ws + nWih + nWhh, OUTD, 512);
    p.wih = ws;                p.wih_sI = 1;   p.wih_sK = G4;
    p.whh = ws + nWih;         p.whh_sI = 1;   p.whh_sK = G4;
    p.outW = ws + nWih + nWhh; p.outW_sK = OUTD; p.outW_sO = 1;
  } else {
    p.wih = w_ih;  p.wih_sI = ZD;  p.wih_sK = 1;
    p.whh = w_hh;  p.whh_sI = HCC; p.whh_sK = 1;
    p.outW = out_W; p.outW_sK = 1; p.outW_sO = 512;
  }

  ntm_main<<<dim3(BB), dim3(1024), 0, stream>>>(p);
}

// Round 6
// 30188.968 us; speedup vs baseline: 2.2604x; 2.2604x over previous
//
#include <hip/hip_runtime.h>
#include <cstdint>
#include <cstddef>

#define BB   16
#define SS   256
#define IND  128
#define OUTD 256
#define HCC  256
#define G4   1024   // 4*HC
#define ZD   384    // IND + H*M
#define NN   128    // memory units
#define MM   64     // memory dim
#define HH   4      // heads
#define MLD  65     // padded mem row (bank-conflict-free: stride 65 words -> 2-way max)

struct Params {
  const int*   x;
  const float* emb;
  const float* mem0;
  const float* wih; int wih_sI, wih_sK;   // element(i,k) = wih[i*sI + k*sK]
  const float* whh; int whh_sI, whh_sK;
  const float* b_ih; const float* b_hh;
  const float* rk_W; const float* rk_b;
  const float* rb_W; const float* rb_b;
  const float* rg_W; const float* rg_b;
  const float* rs_W; const float* rs_b;
  const float* rgm_W; const float* rgm_b;
  const float* wk_W; const float* wk_b;
  const float* wb_W; const float* wb_b;
  const float* wg_W; const float* wg_b;
  const float* ws_W; const float* ws_b;
  const float* wgm_W; const float* wgm_b;
  const float* er_W; const float* er_b;
  const float* ad_W; const float* ad_b;
  const float* outW; int outW_sK, outW_sO; // element(k,o) = outW[k*sK + o*sO], k<512
  const float* out_b;
  float* out;
};

__device__ __forceinline__ float sigm(float x) { return 1.0f / (1.0f + expf(-x)); }
__device__ __forceinline__ float softplus_f(float x) {
  // stable, matches jax.nn.softplus = logaddexp(x, 0)
  return fmaxf(x, 0.0f) + log1pf(expf(-fabsf(x)));
}

// ---------- prep: tiled transpose dst[C][R] = src[R][C]^T (fp32) ----------
__global__ __launch_bounds__(256) void transpose_k(const float* __restrict__ src,
                                                   float* __restrict__ dst,
                                                   int R, int C) {
  __shared__ float tile[32][33];
  const int bx = blockIdx.x * 32;  // over C
  const int by = blockIdx.y * 32;  // over R
  const int tx = threadIdx.x, ty = threadIdx.y; // 32x8
  for (int i = ty; i < 32; i += 8) {
    int r = by + i, c = bx + tx;
    if (r < R && c < C) tile[i][tx] = src[(size_t)r * C + c];
  }
  __syncthreads();
  for (int i = ty; i < 32; i += 8) {
    int c = bx + i, r = by + tx;
    if (c < C && r < R) dst[(size_t)c * R + r] = tile[tx][i];
  }
}

// ---------- main persistent NTM kernel: one block per batch element ----------
// fp32 everywhere (np-ref drift tolerance allows it; fp64 was 68ms from
// software transcendentals). Circular-conv index fix retained.
__global__ __launch_bounds__(1024) void ntm_main(Params p) {
  __shared__ float mem[NN][MLD];                       // 33.3 KB
  __shared__ __attribute__((aligned(16))) float h_s[HCC];
  __shared__ float c_s[HCC];
  __shared__ __attribute__((aligned(16))) float z_s[ZD];
  __shared__ float gates_s[G4];
  __shared__ float rv_s[HH * MM];
  __shared__ float rw_s[HH][NN];
  __shared__ float ww_s[HH][NN];
  __shared__ float rk_s[HH][MM];
  __shared__ float wk_s[HH][MM];
  __shared__ float ev_s[HH][MM];
  __shared__ float av_s[HH][MM];
  __shared__ float scal_s[6][HH];                      // rb,rg,rgm,wb,wg,wgm (activated)
  __shared__ float shift_s[2][HH][3];                  // raw shift logits (r,w)
  __shared__ float memnorm[NN];
  __shared__ float wavescr[8][NN];
  __shared__ float part_s[6][OUTD];

  const int b = blockIdx.x;
  const int tid = threadIdx.x;

  // ---- init state ----
  for (int i = tid; i < NN * MM; i += 1024) mem[i >> 6][i & 63] = p.mem0[i];
  if (tid < HCC) { h_s[tid] = 0.0f; c_s[tid] = 0.0f; }
  if (tid < HH * NN) { rw_s[tid >> 7][tid & 127] = 0.0f; ww_s[tid >> 7][tid & 127] = 0.0f; }
  if (tid < HH * MM) rv_s[tid] = 0.0f;
  __syncthreads();

  for (int t = 0; t < SS; ++t) {
    // ---- P0: memory row norms + build z = [emb(x_t), rv] ----
    if (tid < NN) {
      float s = 0.0f;
      #pragma unroll 8
      for (int m = 0; m < MM; ++m) { float v = mem[tid][m]; s += v * v; }
      memnorm[tid] = fmaxf(sqrtf(s), 1e-12f);
    } else if (tid < NN + ZD) {
      int k = tid - NN;
      if (k < IND) {
        int xbt = p.x[b * SS + t];
        z_s[k] = p.emb[(size_t)xbt * IND + k];
      } else {
        z_s[k] = rv_s[k - IND];
      }
    }
    __syncthreads();

    // ---- P1: gates[i] = W_ih z + W_hh h + b  (each thread one of 1024 outputs) ----
    {
      const int i = tid;
      float acc = p.b_ih[i] + p.b_hh[i];
      {
        const float* wp = p.wih + (size_t)i * p.wih_sI;
        const int sK = p.wih_sK;
        #pragma unroll 4
        for (int j = 0; j < ZD / 4; ++j) {
          const float* w4 = wp + (size_t)(4 * j) * sK;
          acc += w4[0]      * z_s[4 * j]
               + w4[sK]     * z_s[4 * j + 1]
               + w4[2 * sK] * z_s[4 * j + 2]
               + w4[3 * sK] * z_s[4 * j + 3];
        }
      }
      {
        const float* wp = p.whh + (size_t)i * p.whh_sI;
        const int sK = p.whh_sK;
        #pragma unroll 4
        for (int j = 0; j < HCC / 4; ++j) {
          const float* w4 = wp + (size_t)(4 * j) * sK;
          acc += w4[0]      * h_s[4 * j]
               + w4[sK]     * h_s[4 * j + 1]
               + w4[2 * sK] * h_s[4 * j + 2]
               + w4[3 * sK] * h_s[4 * j + 3];
        }
      }
      gates_s[i] = acc;
    }
    __syncthreads();

    // ---- P2: LSTM cell update (torch gate order i,f,g,o) ----
    if (tid < HCC) {
      float gi = gates_s[tid], gf = gates_s[HCC + tid];
      float gg = gates_s[2 * HCC + tid], go = gates_s[3 * HCC + tid];
      float cn = sigm(gf) * c_s[tid] + sigm(gi) * tanhf(gg);
      c_s[tid] = cn;
      h_s[tid] = sigm(go) * tanhf(cn);
    }
    __syncthreads();

    // ---- P3: head linears (vec: rk,wk,er->ev,ad->av; scalars: b,g,gm,shift) ----
    {
      const int a = tid >> 8, idx = tid & 255, hh = idx >> 6, m = idx & 63;
      const float* W; const float* bb;
      if (a == 0)      { W = p.rk_W; bb = p.rk_b; }
      else if (a == 1) { W = p.wk_W; bb = p.wk_b; }
      else if (a == 2) { W = p.er_W; bb = p.er_b; }
      else             { W = p.ad_W; bb = p.ad_b; }
      const float* Wp = W + (size_t)(hh * HCC) * MM + m;
      float acc = bb[hh * MM + m];
      #pragma unroll 4
      for (int j = 0; j < HCC / 4; ++j) {
        const float* w4 = Wp + (size_t)(4 * j) * MM;
        acc += w4[0]      * h_s[4 * j]
             + w4[MM]     * h_s[4 * j + 1]
             + w4[2 * MM] * h_s[4 * j + 2]
             + w4[3 * MM] * h_s[4 * j + 3];
      }
      if (a == 0)      rk_s[hh][m] = acc;
      else if (a == 1) wk_s[hh][m] = acc;
      else if (a == 2) ev_s[hh][m] = sigm(acc);
      else             av_s[hh][m] = tanhf(acc);

      if (tid < 48) {
        if (tid < 24) {
          int pp = tid >> 2, h2 = tid & 3;
          const float* W2; const float* b2;
          switch (pp) {
            case 0:  W2 = p.rb_W;  b2 = p.rb_b;  break;
            case 1:  W2 = p.rg_W;  b2 = p.rg_b;  break;
            case 2:  W2 = p.rgm_W; b2 = p.rgm_b; break;
            case 3:  W2 = p.wb_W;  b2 = p.wb_b;  break;
            case 4:  W2 = p.wg_W;  b2 = p.wg_b;  break;
            default: W2 = p.wgm_W; b2 = p.wgm_b; break;
          }
          float acc2 = b2[h2];
          const float* w2 = W2 + (size_t)h2 * HCC;
          #pragma unroll 4
          for (int c = 0; c < HCC; ++c) acc2 += h_s[c] * w2[c];
          float r;
          if (pp == 1 || pp == 4) r = sigm(acc2);
          else { r = softplus_f(acc2); if (pp == 2 || pp == 5) r += 1.0f; }
          scal_s[pp][h2] = r;
        } else {
          int q = tid - 24, pre = q / 12, rr = q % 12, h2 = rr / 3, j = rr % 3;
          const float* W2 = pre ? p.ws_W : p.rs_W;
          const float* b2 = pre ? p.ws_b : p.rs_b;
          float acc2 = b2[h2 * 3 + j];
          const float* w2 = W2 + (size_t)(h2 * HCC) * 3 + j;
          #pragma unroll 4
          for (int c = 0; c < HCC; ++c) acc2 += h_s[c] * w2[(size_t)c * 3];
          shift_s[pre][h2][j] = acc2;
        }
      }
    }
    __syncthreads();

    // ---- P4: addressing (waves 0..7 = {read,write} x 4 heads); waves 8..15: out h-part ----
    {
      const int w = tid >> 6, l = tid & 63;
      if (w < 8) {
        const int isW = w >> 2, hh = w & 3;
        const float* kv = isW ? wk_s[hh] : rk_s[hh];
        float* prevw = isW ? ww_s[hh] : rw_s[hh];
        const float beta  = scal_s[isW ? 3 : 0][hh];
        const float g     = scal_s[isW ? 4 : 1][hh];
        const float gamma = scal_s[isW ? 5 : 2][hh];
        // ||k||
        float kl = kv[l];
        float kn2 = kl * kl;
        #pragma unroll
        for (int d = 1; d < 64; d <<= 1) kn2 += __shfl_xor(kn2, d, 64);
        const float kn = fmaxf(sqrtf(kn2), 1e-12f);
        // cosine sim * beta for rows n=l and n=l+64
        float s0 = 0.0f, s1 = 0.0f;
        #pragma unroll 4
        for (int m = 0; m < MM; ++m) {
          float km = kv[m];
          s0 += mem[l][m] * km;
          s1 += mem[l + 64][m] * km;
        }
        float v0 = beta * (s0 / (memnorm[l] * kn));
        float v1 = beta * (s1 / (memnorm[l + 64] * kn));
        // softmax over 128
        float mx = fmaxf(v0, v1);
        #pragma unroll
        for (int d = 1; d < 64; d <<= 1) mx = fmaxf(mx, __shfl_xor(mx, d, 64));
        float e0 = expf(v0 - mx), e1 = expf(v1 - mx);
        float sm = e0 + e1;
        #pragma unroll
        for (int d = 1; d < 64; d <<= 1) sm += __shfl_xor(sm, d, 64);
        const float inv = 1.0f / sm;
        // interpolation gate
        float wg0 = g * (e0 * inv) + (1.0f - g) * prevw[l];
        float wg1 = g * (e1 * inv) + (1.0f - g) * prevw[l + 64];
        wavescr[w][l] = wg0;
        wavescr[w][l + 64] = wg1;
        // shift softmax (3)
        float sh0 = shift_s[isW][hh][0], sh1 = shift_s[isW][hh][1], sh2 = shift_s[isW][hh][2];
        float shm = fmaxf(sh0, fmaxf(sh1, sh2));
        float es0 = expf(sh0 - shm), es1 = expf(sh1 - shm), es2 = expf(sh2 - shm);
        float esum = es0 + es1 + es2;
        es0 /= esum; es1 /= esum; es2 /= esum;
        // circular conv: w_[n] = s0*wg[n+1] + s1*wg[n] + s2*wg[n-1]  (mod 128)
        float w_0 = es0 * wavescr[w][(l + 1) & 127] + es1 * wavescr[w][l]
                  + es2 * wavescr[w][(l + 127) & 127];
        const int n1 = l + 64;
        float w_1 = es0 * wavescr[w][(n1 + 1) & 127] + es1 * wavescr[w][n1]
                  + es2 * wavescr[w][(n1 + 127) & 127];   // fixed index
        // sharpen + renormalize
        float p0 = powf(w_0, gamma), p1 = powf(w_1, gamma);
        float tot = p0 + p1;
        #pragma unroll
        for (int d = 1; d < 64; d <<= 1) tot += __shfl_xor(tot, d, 64);
        const float invt = 1.0f / tot;
        prevw[l] = p0 * invt;
        prevw[l + 64] = p1 * invt;
      } else {
        // logits partials for the h half (k = 0..255)
        const int o = tid & 255, hf = (tid - 512) >> 8;  // hf in {0,1}
        const float* Wp = p.outW + (size_t)o * p.outW_sO + (size_t)(hf * 128) * p.outW_sK;
        const int sK = p.outW_sK;
        float acc = 0.0f;
        const float* hp = h_s + hf * 128;
        #pragma unroll 4
        for (int k = 0; k < 128; ++k) acc += hp[k] * Wp[(size_t)k * sK];
        part_s[hf][o] = acc;
      }
    }
    __syncthreads();

    // ---- P5: read vector rv[h][m] = sum_n rw[h][n] * mem[n][m] (OLD mem) ----
    if (tid < HH * MM) {
      const int hh = tid >> 6, m = tid & 63;
      float acc = 0.0f;
      #pragma unroll 4
      for (int n = 0; n < NN; ++n) acc += rw_s[hh][n] * mem[n][m];
      rv_s[tid] = acc;
    }
    __syncthreads();

    // ---- P6: memory write (erase+add) + logits partials for rv half ----
    {
      const int n = tid >> 3, j = tid & 7, m0 = j * 8;
      const float w0 = ww_s[0][n], w1 = ww_s[1][n], w2 = ww_s[2][n], w3 = ww_s[3][n];
      #pragma unroll
      for (int m = m0; m < m0 + 8; ++m) {
        float e  = w0 * ev_s[0][m] + w1 * ev_s[1][m] + w2 * ev_s[2][m] + w3 * ev_s[3][m];
        float aa = w0 * av_s[0][m] + w1 * av_s[1][m] + w2 * av_s[2][m] + w3 * av_s[3][m];
        mem[n][m] = mem[n][m] * (1.0f - e) + aa;
      }
      const int o = tid & 255, hf = tid >> 8;  // hf in 0..3
      const float* Wp = p.outW + (size_t)o * p.outW_sO + (size_t)(HCC + hf * 64) * p.outW_sK;
      const int sK = p.outW_sK;
      float acc = 0.0f;
      const float* rvp = rv_s + hf * 64;
      #pragma unroll 4
      for (int k = 0; k < 64; ++k) acc += rvp[k] * Wp[(size_t)k * sK];
      part_s[2 + hf][o] = acc;
    }
    __syncthreads();

    // ---- P7: logits = sum(partials) + bias -> global ----
    if (tid < OUTD) {
      float r = part_s[0][tid] + part_s[1][tid] + part_s[2][tid]
              + part_s[3][tid] + part_s[4][tid] + part_s[5][tid] + p.out_b[tid];
      p.out[((size_t)b * SS + t) * OUTD + tid] = r;
    }
    __syncthreads();
  }
}

extern "C" void kernel_launch(void* const* d_in, const int* in_sizes, int n_in,
                              void* d_out, int out_size, void* d_ws, size_t ws_size,
                              hipStream_t stream) {
  const int*   x     = (const int*)d_in[0];
  const float* emb   = (const float*)d_in[1];
  const float* mem0  = (const float*)d_in[2];
  const float* w_ih  = (const float*)d_in[3];
  const float* w_hh  = (const float*)d_in[4];
  const float* b_ih  = (const float*)d_in[5];
  const float* b_hh  = (const float*)d_in[6];
  const float* rk_W  = (const float*)d_in[7];
  const float* rk_b  = (const float*)d_in[8];
  const float* rb_W  = (const float*)d_in[9];
  const float* rb_b  = (const float*)d_in[10];
  const float* rg_W  = (const float*)d_in[11];
  const float* rg_b  = (const float*)d_in[12];
  const float* rs_W  = (const float*)d_in[13];
  const float* rs_b  = (const float*)d_in[14];
  const float* rgm_W = (const float*)d_in[15];
  const float* rgm_b = (const float*)d_in[16];
  const float* wk_W  = (const float*)d_in[17];
  const float* wk_b  = (const float*)d_in[18];
  const float* wb_W  = (const float*)d_in[19];
  const float* wb_b  = (const float*)d_in[20];
  const float* wg_W  = (const float*)d_in[21];
  const float* wg_b  = (const float*)d_in[22];
  const float* ws_W  = (const float*)d_in[23];
  const float* ws_b  = (const float*)d_in[24];
  const float* wgm_W = (const float*)d_in[25];
  const float* wgm_b = (const float*)d_in[26];
  const float* er_W  = (const float*)d_in[27];
  const float* er_b  = (const float*)d_in[28];
  const float* ad_W  = (const float*)d_in[29];
  const float* ad_b  = (const float*)d_in[30];
  const float* out_W = (const float*)d_in[31];
  const float* out_b = (const float*)d_in[32];
  float* out = (float*)d_out;

  Params p{};
  p.x = x; p.emb = emb; p.mem0 = mem0;
  p.b_ih = b_ih; p.b_hh = b_hh;
  p.rk_W = rk_W; p.rk_b = rk_b; p.rb_W = rb_W; p.rb_b = rb_b;
  p.rg_W = rg_W; p.rg_b = rg_b; p.rs_W = rs_W; p.rs_b = rs_b;
  p.rgm_W = rgm_W; p.rgm_b = rgm_b;
  p.wk_W = wk_W; p.wk_b = wk_b; p.wb_W = wb_W; p.wb_b = wb_b;
  p.wg_W = wg_W; p.wg_b = wg_b; p.ws_W = ws_W; p.ws_b = ws_b;
  p.wgm_W = wgm_W; p.wgm_b = wgm_b;
  p.er_W = er_W; p.er_b = er_b; p.ad_W = ad_W; p.ad_b = ad_b;
  p.out_b = out_b; p.out = out;

  const size_t nWih = (size_t)ZD * G4;      // 393216
  const size_t nWhh = (size_t)HCC * G4;     // 262144
  const size_t nWout = (size_t)512 * OUTD;  // 131072
  const size_t needT = (nWih + nWhh + nWout) * sizeof(float);
  float* ws = (float*)d_ws;

  if (ws_size >= needT) {
    dim3 blk(32, 8);
    transpose_k<<<dim3(ZD / 32, G4 / 32), blk, 0, stream>>>(w_ih, ws, G4, ZD);
    transpose_k<<<dim3(HCC / 32, G4 / 32), blk, 0, stream>>>(w_hh, ws + nWih, G4, HCC);
    transpose_k<<<dim3(512 / 32, OUTD / 32), blk, 0, stream>>>(out_W, ws + nWih + nWhh, OUTD, 512);
    p.wih = ws;                p.wih_sI = 1;   p.wih_sK = G4;
    p.whh = ws + nWih;         p.whh_sI = 1;   p.whh_sK = G4;
    p.outW = ws + nWih + nWhh; p.outW_sK = OUTD; p.outW_sO = 1;
  } else {
    p.wih = w_ih;  p.wih_sI = ZD;  p.wih_sK = 1;
    p.whh = w_hh;  p.whh_sI = HCC; p.whh_sK = 1;
    p.outW = out_W; p.outW_sK = 1; p.outW_sO = 512;
  }

  ntm_main<<<dim3(BB), dim3(1024), 0, stream>>>(p);
}

// Round 7
// 28883.978 us; speedup vs baseline: 2.3625x; 1.0452x over previous
//
#include <hip/hip_runtime.h>
#include <cstdint>
#include <cstddef>

#define BB   16
#define SS   256
#define IND  128
#define OUTD 256
#define HCC  256
#define G4   1024   // 4*HC
#define ZD   384    // IND + H*M
#define KTOT 640    // ZD + HCC (combined gates GEMV depth)
#define NN   128    // memory units
#define MM   64     // memory dim
#define HH   4      // heads
#define MLD  65     // padded mem row

struct Params {
  const int*   x;
  const float* emb;
  const float* mem0;
  const float* wih; int wih_sI, wih_sK;   // generic: element(i,k) = wih[i*sI + k*sK]; fast: combined W^T[640][1024]
  const float* whh; int whh_sI, whh_sK;
  const float* b_ih; const float* b_hh;
  const float* rk_W; const float* rk_b;
  const float* rb_W; const float* rb_b;
  const float* rg_W; const float* rg_b;
  const float* rs_W; const float* rs_b;
  const float* rgm_W; const float* rgm_b;
  const float* wk_W; const float* wk_b;
  const float* wb_W; const float* wb_b;
  const float* wg_W; const float* wg_b;
  const float* ws_W; const float* ws_b;
  const float* wgm_W; const float* wgm_b;
  const float* er_W; const float* er_b;
  const float* ad_W; const float* ad_b;
  const float* outW; int outW_sK, outW_sO; // generic strides; fast: outW^T[512][256]
  const float* out_b;
  float* out;
};

__device__ __forceinline__ float sigm(float x) { return 1.0f / (1.0f + expf(-x)); }
__device__ __forceinline__ float softplus_f(float x) {
  return fmaxf(x, 0.0f) + log1pf(expf(-fabsf(x)));
}

// ---------- prep: tiled transpose dst[C][R] = src[R][C]^T (fp32) ----------
__global__ __launch_bounds__(256) void transpose_k(const float* __restrict__ src,
                                                   float* __restrict__ dst,
                                                   int R, int C) {
  __shared__ float tile[32][33];
  const int bx = blockIdx.x * 32;  // over C
  const int by = blockIdx.y * 32;  // over R
  const int tx = threadIdx.x, ty = threadIdx.y; // 32x8
  for (int i = ty; i < 32; i += 8) {
    int r = by + i, c = bx + tx;
    if (r < R && c < C) tile[i][tx] = src[(size_t)r * C + c];
  }
  __syncthreads();
  for (int i = ty; i < 32; i += 8) {
    int c = bx + i, r = by + tx;
    if (c < C && r < R) dst[(size_t)c * R + r] = tile[tx][i];
  }
}

// =====================================================================
// FAST kernel: transposed weights, uniform-base loads, chunk-16 batching
// =====================================================================
__global__ __launch_bounds__(1024) void ntm_fast(Params p) {
  __shared__ float mem[NN][MLD];
  __shared__ float zh_s[KTOT];          // z (384) then h (256), contiguous
  __shared__ float c_s[HCC];
  __shared__ float gates_s[G4];
  __shared__ float rv_s[HH * MM];
  __shared__ float rw_s[HH][NN];
  __shared__ float ww_s[HH][NN];
  __shared__ float rk_s[HH][MM];
  __shared__ float wk_s[HH][MM];
  __shared__ float ev_s[HH][MM];
  __shared__ float av_s[HH][MM];
  __shared__ float scal_s[6][HH];
  __shared__ float shift_s[2][HH][3];
  __shared__ float memnorm[NN];
  __shared__ float wavescr[8][NN];
  __shared__ float part_s[6][OUTD];

  const int b    = blockIdx.x;
  const int tid  = threadIdx.x;
  const int lane = tid & 63;
  float* h_s = zh_s + ZD;
  const float* __restrict__ WT = p.wih;   // [640][1024] row-major (k-major)
  const float* __restrict__ OT = p.outW;  // [512][256]

  // wave-uniform ids (force SGPR so loads get s_base + lane*4 form)
  const int wv   = __builtin_amdgcn_readfirstlane(tid >> 6);    // 0..15
  const int a_u  = __builtin_amdgcn_readfirstlane(tid >> 8);    // 0..3
  const int hh_u = __builtin_amdgcn_readfirstlane((tid >> 6) & 3);

  // hoisted per-thread constants (invariant over t)
  const float bias_g = p.b_ih[tid] + p.b_hh[tid];
  const float* W3; const float* b3;
  if (a_u == 0)      { W3 = p.rk_W; b3 = p.rk_b; }
  else if (a_u == 1) { W3 = p.wk_W; b3 = p.wk_b; }
  else if (a_u == 2) { W3 = p.er_W; b3 = p.er_b; }
  else               { W3 = p.ad_W; b3 = p.ad_b; }
  const float bias3 = b3[hh_u * MM + lane];
  const float outb  = (tid < OUTD) ? p.out_b[tid] : 0.0f;
  const int* __restrict__ xrow = p.x + b * SS;

  // ---- init state ----
  for (int i = tid; i < NN * MM; i += 1024) mem[i >> 6][i & 63] = p.mem0[i];
  if (tid < HCC) { h_s[tid] = 0.0f; c_s[tid] = 0.0f; }
  if (tid < HH * NN) { rw_s[tid >> 7][tid & 127] = 0.0f; ww_s[tid >> 7][tid & 127] = 0.0f; }
  if (tid < HH * MM) rv_s[tid] = 0.0f;
  __syncthreads();

  for (int t = 0; t < SS; ++t) {
    // ---- P0: memory row norms + build z = [emb(x_t), rv] ----
    if (tid < NN) {
      float s = 0.0f;
      #pragma unroll 8
      for (int m = 0; m < MM; ++m) { float v = mem[tid][m]; s += v * v; }
      memnorm[tid] = fmaxf(sqrtf(s), 1e-12f);
    } else if (tid < NN + ZD) {
      int k = tid - NN;
      if (k < IND) {
        int xbt = xrow[t];
        zh_s[k] = p.emb[(size_t)xbt * IND + k];
      } else {
        zh_s[k] = rv_s[k - IND];
      }
    }
    __syncthreads();

    // ---- P1: gates[i] = W^T[:,i] . [z;h] + b  (combined 640-deep GEMV) ----
    {
      float acc = bias_g;
      for (int c = 0; c < KTOT / 16; ++c) {
        float buf[16];
        #pragma unroll
        for (int u = 0; u < 16; ++u) buf[u] = WT[(size_t)(c * 16 + u) * G4 + tid];
        #pragma unroll
        for (int u = 0; u < 16; ++u) acc += buf[u] * zh_s[c * 16 + u];
      }
      gates_s[tid] = acc;
    }
    __syncthreads();

    // ---- P2: LSTM cell update (torch gate order i,f,g,o) ----
    if (tid < HCC) {
      float gi = gates_s[tid], gf = gates_s[HCC + tid];
      float gg = gates_s[2 * HCC + tid], go = gates_s[3 * HCC + tid];
      float cn = sigm(gf) * c_s[tid] + sigm(gi) * tanhf(gg);
      c_s[tid] = cn;
      h_s[tid] = sigm(go) * tanhf(cn);
    }
    __syncthreads();

    // ---- P3: head vec-linears (all waves) + 48 scalar dots (3 per wave) ----
    {
      float acc = bias3;
      for (int cc = 0; cc < HCC / 16; ++cc) {
        float buf[16];
        #pragma unroll
        for (int u = 0; u < 16; ++u)
          buf[u] = W3[(size_t)(hh_u * HCC + cc * 16 + u) * MM + lane];
        #pragma unroll
        for (int u = 0; u < 16; ++u) acc += buf[u] * h_s[cc * 16 + u];
      }
      if (a_u == 0)      rk_s[hh_u][lane] = acc;
      else if (a_u == 1) wk_s[hh_u][lane] = acc;
      else if (a_u == 2) ev_s[hh_u][lane] = sigm(acc);
      else               av_s[hh_u][lane] = tanhf(acc);

      // scalar/shift dots: d = 3*wv + r, d in [0,48)
      #pragma unroll
      for (int r = 0; r < 3; ++r) {
        const int d = wv * 3 + r;
        float partial = 0.0f;
        if (d < 24) {
          const int pp = d >> 2, h2 = d & 3;
          const float* W2 = (pp == 0) ? p.rb_W : (pp == 1) ? p.rg_W : (pp == 2) ? p.rgm_W
                          : (pp == 3) ? p.wb_W : (pp == 4) ? p.wg_W : p.wgm_W;
          #pragma unroll
          for (int q = 0; q < 4; ++q)
            partial += h_s[64 * q + lane] * W2[h2 * HCC + 64 * q + lane];
          #pragma unroll
          for (int dd = 1; dd < 64; dd <<= 1) partial += __shfl_xor(partial, dd, 64);
          if (lane == 0) {
            const float* b2 = (pp == 0) ? p.rb_b : (pp == 1) ? p.rg_b : (pp == 2) ? p.rgm_b
                            : (pp == 3) ? p.wb_b : (pp == 4) ? p.wg_b : p.wgm_b;
            float acc2 = partial + b2[h2];
            float rres;
            if (pp == 1 || pp == 4) rres = sigm(acc2);
            else { rres = softplus_f(acc2); if (pp == 2 || pp == 5) rres += 1.0f; }
            scal_s[pp][h2] = rres;
          }
        } else {
          const int q = d - 24, pre = q / 12, rr = q % 12, h2 = rr / 3, jj = rr % 3;
          const float* W2 = pre ? p.ws_W : p.rs_W;
          #pragma unroll
          for (int qq = 0; qq < 4; ++qq)
            partial += h_s[64 * qq + lane] * W2[(size_t)(h2 * HCC + 64 * qq + lane) * 3 + jj];
          #pragma unroll
          for (int dd = 1; dd < 64; dd <<= 1) partial += __shfl_xor(partial, dd, 64);
          if (lane == 0) {
            const float* b2 = pre ? p.ws_b : p.rs_b;
            shift_s[pre][h2][jj] = partial + b2[h2 * 3 + jj];
          }
        }
      }
    }
    __syncthreads();

    // ---- P4: addressing (waves 0..7); waves 8..15: out_W h-part GEMV ----
    {
      if (wv < 8) {
        const int isW = wv >> 2, hh = wv & 3;
        const int l = lane;
        const float* kv = isW ? wk_s[hh] : rk_s[hh];
        float* prevw = isW ? ww_s[hh] : rw_s[hh];
        const float beta  = scal_s[isW ? 3 : 0][hh];
        const float g     = scal_s[isW ? 4 : 1][hh];
        const float gamma = scal_s[isW ? 5 : 2][hh];
        float kl = kv[l];
        float kn2 = kl * kl;
        #pragma unroll
        for (int d = 1; d < 64; d <<= 1) kn2 += __shfl_xor(kn2, d, 64);
        const float kn = fmaxf(sqrtf(kn2), 1e-12f);
        float s0 = 0.0f, s1 = 0.0f;
        #pragma unroll 4
        for (int m = 0; m < MM; ++m) {
          float km = kv[m];
          s0 += mem[l][m] * km;
          s1 += mem[l + 64][m] * km;
        }
        float v0 = beta * (s0 / (memnorm[l] * kn));
        float v1 = beta * (s1 / (memnorm[l + 64] * kn));
        float mx = fmaxf(v0, v1);
        #pragma unroll
        for (int d = 1; d < 64; d <<= 1) mx = fmaxf(mx, __shfl_xor(mx, d, 64));
        float e0 = expf(v0 - mx), e1 = expf(v1 - mx);
        float sm = e0 + e1;
        #pragma unroll
        for (int d = 1; d < 64; d <<= 1) sm += __shfl_xor(sm, d, 64);
        const float inv = 1.0f / sm;
        float wg0 = g * (e0 * inv) + (1.0f - g) * prevw[l];
        float wg1 = g * (e1 * inv) + (1.0f - g) * prevw[l + 64];
        wavescr[wv][l] = wg0;
        wavescr[wv][l + 64] = wg1;
        float sh0 = shift_s[isW][hh][0], sh1 = shift_s[isW][hh][1], sh2 = shift_s[isW][hh][2];
        float shm = fmaxf(sh0, fmaxf(sh1, sh2));
        float es0 = expf(sh0 - shm), es1 = expf(sh1 - shm), es2 = expf(sh2 - shm);
        float esum = es0 + es1 + es2;
        es0 /= esum; es1 /= esum; es2 /= esum;
        float w_0 = es0 * wavescr[wv][(l + 1) & 127] + es1 * wavescr[wv][l]
                  + es2 * wavescr[wv][(l + 127) & 127];
        const int n1 = l + 64;
        float w_1 = es0 * wavescr[wv][(n1 + 1) & 127] + es1 * wavescr[wv][n1]
                  + es2 * wavescr[wv][(n1 + 127) & 127];
        float p0 = powf(w_0, gamma), p1 = powf(w_1, gamma);
        float tot = p0 + p1;
        #pragma unroll
        for (int d = 1; d < 64; d <<= 1) tot += __shfl_xor(tot, d, 64);
        const float invt = 1.0f / tot;
        prevw[l] = p0 * invt;
        prevw[l + 64] = p1 * invt;
      } else {
        const int hf = (wv - 8) >> 2;      // 0 or 1 (uniform)
        const int og = wv & 3;             // o = og*64 + lane == tid & 255
        float acc = 0.0f;
        for (int cc = 0; cc < 8; ++cc) {
          float buf[16];
          #pragma unroll
          for (int u = 0; u < 16; ++u)
            buf[u] = OT[(size_t)(hf * 128 + cc * 16 + u) * OUTD + og * 64 + lane];
          #pragma unroll
          for (int u = 0; u < 16; ++u) acc += buf[u] * h_s[hf * 128 + cc * 16 + u];
        }
        part_s[hf][og * 64 + lane] = acc;
      }
    }
    __syncthreads();

    // ---- P5: read vector rv[h][m] = sum_n rw[h][n] * mem[n][m] (OLD mem) ----
    if (tid < HH * MM) {
      float acc = 0.0f;
      #pragma unroll 4
      for (int n = 0; n < NN; ++n) acc += rw_s[wv][n] * mem[n][lane];
      rv_s[tid] = acc;
    }
    __syncthreads();

    // ---- P6: memory write (erase+add) + out_W rv-part GEMV ----
    {
      const int n = tid >> 3, j = tid & 7, m0 = j * 8;
      const float w0 = ww_s[0][n], w1 = ww_s[1][n], w2 = ww_s[2][n], w3 = ww_s[3][n];
      #pragma unroll
      for (int m = m0; m < m0 + 8; ++m) {
        float e  = w0 * ev_s[0][m] + w1 * ev_s[1][m] + w2 * ev_s[2][m] + w3 * ev_s[3][m];
        float aa = w0 * av_s[0][m] + w1 * av_s[1][m] + w2 * av_s[2][m] + w3 * av_s[3][m];
        mem[n][m] = mem[n][m] * (1.0f - e) + aa;
      }
      const int hf6 = wv >> 2;             // == tid >> 8 (uniform)
      const int og6 = wv & 3;
      float acc = 0.0f;
      for (int cc = 0; cc < 4; ++cc) {
        float buf[16];
        #pragma unroll
        for (int u = 0; u < 16; ++u)
          buf[u] = OT[(size_t)(HCC + hf6 * 64 + cc * 16 + u) * OUTD + og6 * 64 + lane];
        #pragma unroll
        for (int u = 0; u < 16; ++u) acc += buf[u] * rv_s[hf6 * 64 + cc * 16 + u];
      }
      part_s[2 + hf6][og6 * 64 + lane] = acc;
    }
    __syncthreads();

    // ---- P7: logits = sum(partials) + bias -> global ----
    if (tid < OUTD) {
      float r = part_s[0][tid] + part_s[1][tid] + part_s[2][tid]
              + part_s[3][tid] + part_s[4][tid] + part_s[5][tid] + outb;
      p.out[((size_t)b * SS + t) * OUTD + tid] = r;
    }
    __syncthreads();
  }
}

// =====================================================================
// GENERIC fallback (R6 kernel, runtime strides) — used if ws too small
// =====================================================================
__global__ __launch_bounds__(1024) void ntm_generic(Params p) {
  __shared__ float mem[NN][MLD];
  __shared__ __attribute__((aligned(16))) float h_s[HCC];
  __shared__ float c_s[HCC];
  __shared__ __attribute__((aligned(16))) float z_s[ZD];
  __shared__ float gates_s[G4];
  __shared__ float rv_s[HH * MM];
  __shared__ float rw_s[HH][NN];
  __shared__ float ww_s[HH][NN];
  __shared__ float rk_s[HH][MM];
  __shared__ float wk_s[HH][MM];
  __shared__ float ev_s[HH][MM];
  __shared__ float av_s[HH][MM];
  __shared__ float scal_s[6][HH];
  __shared__ float shift_s[2][HH][3];
  __shared__ float memnorm[NN];
  __shared__ float wavescr[8][NN];
  __shared__ float part_s[6][OUTD];

  const int b = blockIdx.x;
  const int tid = threadIdx.x;

  for (int i = tid; i < NN * MM; i += 1024) mem[i >> 6][i & 63] = p.mem0[i];
  if (tid < HCC) { h_s[tid] = 0.0f; c_s[tid] = 0.0f; }
  if (tid < HH * NN) { rw_s[tid >> 7][tid & 127] = 0.0f; ww_s[tid >> 7][tid & 127] = 0.0f; }
  if (tid < HH * MM) rv_s[tid] = 0.0f;
  __syncthreads();

  for (int t = 0; t < SS; ++t) {
    if (tid < NN) {
      float s = 0.0f;
      #pragma unroll 8
      for (int m = 0; m < MM; ++m) { float v = mem[tid][m]; s += v * v; }
      memnorm[tid] = fmaxf(sqrtf(s), 1e-12f);
    } else if (tid < NN + ZD) {
      int k = tid - NN;
      if (k < IND) {
        int xbt = p.x[b * SS + t];
        z_s[k] = p.emb[(size_t)xbt * IND + k];
      } else {
        z_s[k] = rv_s[k - IND];
      }
    }
    __syncthreads();

    {
      const int i = tid;
      float acc = p.b_ih[i] + p.b_hh[i];
      {
        const float* wp = p.wih + (size_t)i * p.wih_sI;
        const int sK = p.wih_sK;
        #pragma unroll 4
        for (int j = 0; j < ZD / 4; ++j) {
          const float* w4 = wp + (size_t)(4 * j) * sK;
          acc += w4[0] * z_s[4 * j] + w4[sK] * z_s[4 * j + 1]
               + w4[2 * sK] * z_s[4 * j + 2] + w4[3 * sK] * z_s[4 * j + 3];
        }
      }
      {
        const float* wp = p.whh + (size_t)i * p.whh_sI;
        const int sK = p.whh_sK;
        #pragma unroll 4
        for (int j = 0; j < HCC / 4; ++j) {
          const float* w4 = wp + (size_t)(4 * j) * sK;
          acc += w4[0] * h_s[4 * j] + w4[sK] * h_s[4 * j + 1]
               + w4[2 * sK] * h_s[4 * j + 2] + w4[3 * sK] * h_s[4 * j + 3];
        }
      }
      gates_s[i] = acc;
    }
    __syncthreads();

    if (tid < HCC) {
      float gi = gates_s[tid], gf = gates_s[HCC + tid];
      float gg = gates_s[2 * HCC + tid], go = gates_s[3 * HCC + tid];
      float cn = sigm(gf) * c_s[tid] + sigm(gi) * tanhf(gg);
      c_s[tid] = cn;
      h_s[tid] = sigm(go) * tanhf(cn);
    }
    __syncthreads();

    {
      const int a = tid >> 8, idx = tid & 255, hh = idx >> 6, m = idx & 63;
      const float* W; const float* bb;
      if (a == 0)      { W = p.rk_W; bb = p.rk_b; }
      else if (a == 1) { W = p.wk_W; bb = p.wk_b; }
      else if (a == 2) { W = p.er_W; bb = p.er_b; }
      else             { W = p.ad_W; bb = p.ad_b; }
      const float* Wp = W + (size_t)(hh * HCC) * MM + m;
      float acc = bb[hh * MM + m];
      #pragma unroll 4
      for (int j = 0; j < HCC / 4; ++j) {
        const float* w4 = Wp + (size_t)(4 * j) * MM;
        acc += w4[0] * h_s[4 * j] + w4[MM] * h_s[4 * j + 1]
             + w4[2 * MM] * h_s[4 * j + 2] + w4[3 * MM] * h_s[4 * j + 3];
      }
      if (a == 0)      rk_s[hh][m] = acc;
      else if (a == 1) wk_s[hh][m] = acc;
      else if (a == 2) ev_s[hh][m] = sigm(acc);
      else             av_s[hh][m] = tanhf(acc);

      if (tid < 48) {
        if (tid < 24) {
          int pp = tid >> 2, h2 = tid & 3;
          const float* W2; const float* b2;
          switch (pp) {
            case 0:  W2 = p.rb_W;  b2 = p.rb_b;  break;
            case 1:  W2 = p.rg_W;  b2 = p.rg_b;  break;
            case 2:  W2 = p.rgm_W; b2 = p.rgm_b; break;
            case 3:  W2 = p.wb_W;  b2 = p.wb_b;  break;
            case 4:  W2 = p.wg_W;  b2 = p.wg_b;  break;
            default: W2 = p.wgm_W; b2 = p.wgm_b; break;
          }
          float acc2 = b2[h2];
          const float* w2 = W2 + (size_t)h2 * HCC;
          #pragma unroll 4
          for (int c = 0; c < HCC; ++c) acc2 += h_s[c] * w2[c];
          float r;
          if (pp == 1 || pp == 4) r = sigm(acc2);
          else { r = softplus_f(acc2); if (pp == 2 || pp == 5) r += 1.0f; }
          scal_s[pp][h2] = r;
        } else {
          int q = tid - 24, pre = q / 12, rr = q % 12, h2 = rr / 3, j = rr % 3;
          const float* W2 = pre ? p.ws_W : p.rs_W;
          const float* b2 = pre ? p.ws_b : p.rs_b;
          float acc2 = b2[h2 * 3 + j];
          const float* w2 = W2 + (size_t)(h2 * HCC) * 3 + j;
          #pragma unroll 4
          for (int c = 0; c < HCC; ++c) acc2 += h_s[c] * w2[(size_t)c * 3];
          shift_s[pre][h2][j] = acc2;
        }
      }
    }
    __syncthreads();

    {
      const int w = tid >> 6, l = tid & 63;
      if (w < 8) {
        const int isW = w >> 2, hh = w & 3;
        const float* kv = isW ? wk_s[hh] : rk_s[hh];
        float* prevw = isW ? ww_s[hh] : rw_s[hh];
        const float beta  = scal_s[isW ? 3 : 0][hh];
        const float g     = scal_s[isW ? 4 : 1][hh];
        const float gamma = scal_s[isW ? 5 : 2][hh];
        float kl = kv[l];
        float kn2 = kl * kl;
        #pragma unroll
        for (int d = 1; d < 64; d <<= 1) kn2 += __shfl_xor(kn2, d, 64);
        const float kn = fmaxf(sqrtf(kn2), 1e-12f);
        float s0 = 0.0f, s1 = 0.0f;
        #pragma unroll 4
        for (int m = 0; m < MM; ++m) {
          float km = kv[m];
          s0 += mem[l][m] * km;
          s1 += mem[l + 64][m] * km;
        }
        float v0 = beta * (s0 / (memnorm[l] * kn));
        float v1 = beta * (s1 / (memnorm[l + 64] * kn));
        float mx = fmaxf(v0, v1);
        #pragma unroll
        for (int d = 1; d < 64; d <<= 1) mx = fmaxf(mx, __shfl_xor(mx, d, 64));
        float e0 = expf(v0 - mx), e1 = expf(v1 - mx);
        float sm = e0 + e1;
        #pragma unroll
        for (int d = 1; d < 64; d <<= 1) sm += __shfl_xor(sm, d, 64);
        const float inv = 1.0f / sm;
        float wg0 = g * (e0 * inv) + (1.0f - g) * prevw[l];
        float wg1 = g * (e1 * inv) + (1.0f - g) * prevw[l + 64];
        wavescr[w][l] = wg0;
        wavescr[w][l + 64] = wg1;
        float sh0 = shift_s[isW][hh][0], sh1 = shift_s[isW][hh][1], sh2 = shift_s[isW][hh][2];
        float shm = fmaxf(sh0, fmaxf(sh1, sh2));
        float es0 = expf(sh0 - shm), es1 = expf(sh1 - shm), es2 = expf(sh2 - shm);
        float esum = es0 + es1 + es2;
        es0 /= esum; es1 /= esum; es2 /= esum;
        float w_0 = es0 * wavescr[w][(l + 1) & 127] + es1 * wavescr[w][l]
                  + es2 * wavescr[w][(l + 127) & 127];
        const int n1 = l + 64;
        float w_1 = es0 * wavescr[w][(n1 + 1) & 127] + es1 * wavescr[w][n1]
                  + es2 * wavescr[w][(n1 + 127) & 127];
        float p0 = powf(w_0, gamma), p1 = powf(w_1, gamma);
        float tot = p0 + p1;
        #pragma unroll
        for (int d = 1; d < 64; d <<= 1) tot += __shfl_xor(tot, d, 64);
        const float invt = 1.0f / tot;
        prevw[l] = p0 * invt;
        prevw[l + 64] = p1 * invt;
      } else {
        const int o = tid & 255, hf = (tid - 512) >> 8;
        const float* Wp = p.outW + (size_t)o * p.outW_sO + (size_t)(hf * 128) * p.outW_sK;
        const int sK = p.outW_sK;
        float acc = 0.0f;
        const float* hp = h_s + hf * 128;
        #pragma unroll 4
        for (int k = 0; k < 128; ++k) acc += hp[k] * Wp[(size_t)k * sK];
        part_s[hf][o] = acc;
      }
    }
    __syncthreads();

    if (tid < HH * MM) {
      const int hh = tid >> 6, m = tid & 63;
      float acc = 0.0f;
      #pragma unroll 4
      for (int n = 0; n < NN; ++n) acc += rw_s[hh][n] * mem[n][m];
      rv_s[tid] = acc;
    }
    __syncthreads();

    {
      const int n = tid >> 3, j = tid & 7, m0 = j * 8;
      const float w0 = ww_s[0][n], w1 = ww_s[1][n], w2 = ww_s[2][n], w3 = ww_s[3][n];
      #pragma unroll
      for (int m = m0; m < m0 + 8; ++m) {
        float e  = w0 * ev_s[0][m] + w1 * ev_s[1][m] + w2 * ev_s[2][m] + w3 * ev_s[3][m];
        float aa = w0 * av_s[0][m] + w1 * av_s[1][m] + w2 * av_s[2][m] + w3 * av_s[3][m];
        mem[n][m] = mem[n][m] * (1.0f - e) + aa;
      }
      const int o = tid & 255, hf = tid >> 8;
      const float* Wp = p.outW + (size_t)o * p.outW_sO + (size_t)(HCC + hf * 64) * p.outW_sK;
      const int sK = p.outW_sK;
      float acc = 0.0f;
      const float* rvp = rv_s + hf * 64;
      #pragma unroll 4
      for (int k = 0; k < 64; ++k) acc += rvp[k] * Wp[(size_t)k * sK];
      part_s[2 + hf][o] = acc;
    }
    __syncthreads();

    if (tid < OUTD) {
      float r = part_s[0][tid] + part_s[1][tid] + part_s[2][tid]
              + part_s[3][tid] + part_s[4][tid] + part_s[5][tid] + p.out_b[tid];
      p.out[((size_t)b * SS + t) * OUTD + tid] = r;
    }
    __syncthreads();
  }
}

extern "C" void kernel_launch(void* const* d_in, const int* in_sizes, int n_in,
                              void* d_out, int out_size, void* d_ws, size_t ws_size,
                              hipStream_t stream) {
  const int*   x     = (const int*)d_in[0];
  const float* emb   = (const float*)d_in[1];
  const float* mem0  = (const float*)d_in[2];
  const float* w_ih  = (const float*)d_in[3];
  const float* w_hh  = (const float*)d_in[4];
  const float* b_ih  = (const float*)d_in[5];
  const float* b_hh  = (const float*)d_in[6];
  const float* rk_W  = (const float*)d_in[7];
  const float* rk_b  = (const float*)d_in[8];
  const float* rb_W  = (const float*)d_in[9];
  const float* rb_b  = (const float*)d_in[10];
  const float* rg_W  = (const float*)d_in[11];
  const float* rg_b  = (const float*)d_in[12];
  const float* rs_W  = (const float*)d_in[13];
  const float* rs_b  = (const float*)d_in[14];
  const float* rgm_W = (const float*)d_in[15];
  const float* rgm_b = (const float*)d_in[16];
  const float* wk_W  = (const float*)d_in[17];
  const float* wk_b  = (const float*)d_in[18];
  const float* wb_W  = (const float*)d_in[19];
  const float* wb_b  = (const float*)d_in[20];
  const float* wg_W  = (const float*)d_in[21];
  const float* wg_b  = (const float*)d_in[22];
  const float* ws_W  = (const float*)d_in[23];
  const float* ws_b  = (const float*)d_in[24];
  const float* wgm_W = (const float*)d_in[25];
  const float* wgm_b = (const float*)d_in[26];
  const float* er_W  = (const float*)d_in[27];
  const float* er_b  = (const float*)d_in[28];
  const float* ad_W  = (const float*)d_in[29];
  const float* ad_b  = (const float*)d_in[30];
  const float* out_W = (const float*)d_in[31];
  const float* out_b = (const float*)d_in[32];
  float* out = (float*)d_out;

  Params p{};
  p.x = x; p.emb = emb; p.mem0 = mem0;
  p.b_ih = b_ih; p.b_hh = b_hh;
  p.rk_W = rk_W; p.rk_b = rk_b; p.rb_W = rb_W; p.rb_b = rb_b;
  p.rg_W = rg_W; p.rg_b = rg_b; p.rs_W = rs_W; p.rs_b = rs_b;
  p.rgm_W = rgm_W; p.rgm_b = rgm_b;
  p.wk_W = wk_W; p.wk_b = wk_b; p.wb_W = wb_W; p.wb_b = wb_b;
  p.wg_W = wg_W; p.wg_b = wg_b; p.ws_W = ws_W; p.ws_b = ws_b;
  p.wgm_W = wgm_W; p.wgm_b = wgm_b;
  p.er_W = er_W; p.er_b = er_b; p.ad_W = ad_W; p.ad_b = ad_b;
  p.out_b = out_b; p.out = out;

  const size_t nWih  = (size_t)ZD * G4;     // 393216 (combined rows 0..383)
  const size_t nWhh  = (size_t)HCC * G4;    // 262144 (combined rows 384..639)
  const size_t nWout = (size_t)512 * OUTD;  // 131072
  const size_t needT = (nWih + nWhh + nWout) * sizeof(float);
  float* ws = (float*)d_ws;

  if (ws_size >= needT) {
    dim3 blk(32, 8);
    // combined W^T: rows 0..383 = w_ih^T, rows 384..639 = w_hh^T  -> [640][1024]
    transpose_k<<<dim3(ZD / 32, G4 / 32), blk, 0, stream>>>(w_ih, ws, G4, ZD);
    transpose_k<<<dim3(HCC / 32, G4 / 32), blk, 0, stream>>>(w_hh, ws + nWih, G4, HCC);
    transpose_k<<<dim3(512 / 32, OUTD / 32), blk, 0, stream>>>(out_W, ws + nWih + nWhh, OUTD, 512);
    p.wih  = ws;                  // combined [640][1024]
    p.outW = ws + nWih + nWhh;    // [512][256]
    ntm_fast<<<dim3(BB), dim3(1024), 0, stream>>>(p);
  } else {
    p.wih = w_ih;  p.wih_sI = ZD;  p.wih_sK = 1;
    p.whh = w_hh;  p.whh_sI = HCC; p.whh_sK = 1;
    p.outW = out_W; p.outW_sK = 1; p.outW_sO = 512;
    ntm_generic<<<dim3(BB), dim3(1024), 0, stream>>>(p);
  }
}

// Round 8
// 11963.190 us; speedup vs baseline: 5.7040x; 2.4144x over previous
//
#include <hip/hip_runtime.h>
#include <hip/hip_cooperative_groups.h>
#include <cstdint>
#include <cstddef>

namespace cg = cooperative_groups;

#define BB   16
#define SS   256
#define IND  128
#define OUTD 256
#define HCC  256
#define G4   1024   // 4*HC
#define ZD   384    // IND + H*M
#define KTOT 640    // ZD + HCC
#define NN   128
#define MM   64
#define HH   4
#define MLD  65

__device__ __forceinline__ float sigm(float x) { return 1.0f / (1.0f + expf(-x)); }
__device__ __forceinline__ float softplus_f(float x) {
  return fmaxf(x, 0.0f) + log1pf(expf(-fabsf(x)));
}

// ====================== cooperative path ======================
// ws float layout:
//  Wg4 [8][160][128][4]   655360   gates slice-major float4 layout
//  Wh4 [8][64][128][4]    262144   vec-head slices
//  Wo4 [8][128][32][4]    131072   out slices (full 512 depth)
//  hbuf[2][16][256]         8192
//  headv[16][1024]         16384
//  scalg[16][24]             384
//  shiftg[16][24]            384
#define NWG 655360
#define NWH 262144
#define NWO 131072
#define NHB 8192
#define NHV 16384
#define NSC 384
#define NSH 384
#define NCOOP (NWG + NWH + NWO + NHB + NHV + NSC + NSH)  // 1,073,920 floats

__global__ __launch_bounds__(256) void prep_g(const float* __restrict__ wih,
                                              const float* __restrict__ whh,
                                              float* __restrict__ dst) {
  int idx = blockIdx.x * 256 + threadIdx.x;
  if (idx >= NWG) return;
  int j  = idx & 3;
  int li = (idx >> 2) & 127;
  int r  = idx >> 9;              // s*160 + k4
  int k4 = r % 160, s = r / 160;
  int g  = li >> 5, jj = li & 31;
  int i  = g * 256 + s * 32 + jj;
  int k  = k4 * 4 + j;
  dst[idx] = (k < ZD) ? wih[(size_t)i * ZD + k] : whh[(size_t)i * HCC + (k - ZD)];
}

__global__ __launch_bounds__(256) void prep_h(const float* __restrict__ rkW,
                                              const float* __restrict__ wkW,
                                              const float* __restrict__ erW,
                                              const float* __restrict__ adW,
                                              float* __restrict__ dst) {
  int idx = blockIdx.x * 256 + threadIdx.x;
  if (idx >= NWH) return;
  int j  = idx & 3;
  int li = (idx >> 2) & 127;
  int r  = idx >> 9;              // s*64 + c4
  int c4 = r & 63, s = r >> 6;
  int oh = s * 128 + li;
  int a = oh >> 8, hh = (oh >> 6) & 3, m = oh & 63;
  int c = c4 * 4 + j;
  const float* W = (a == 0) ? rkW : (a == 1) ? wkW : (a == 2) ? erW : adW;
  dst[idx] = W[((size_t)hh * HCC + c) * MM + m];
}

__global__ __launch_bounds__(256) void prep_o(const float* __restrict__ outW,
                                              float* __restrict__ dst) {
  int idx = blockIdx.x * 256 + threadIdx.x;
  if (idx >= NWO) return;
  int j  = idx & 3;
  int lo = (idx >> 2) & 31;
  int r  = idx >> 7;              // s*128 + k4
  int k4 = r & 127, s = r >> 7;
  int o = s * 32 + lo;
  int k = k4 * 4 + j;
  dst[idx] = outW[(size_t)o * 512 + k];
}

struct CoopP {
  const int* x; const float* emb; const float* mem0;
  const float* Wg; const float* Wh; const float* Wo;
  float* hbuf; float* headv; float* scalg; float* shiftg;
  const float* b_ih; const float* b_hh;
  const float* rk_b; const float* wk_b; const float* er_b; const float* ad_b;
  const float* rb_W; const float* rb_b; const float* rg_W; const float* rg_b;
  const float* rgm_W; const float* rgm_b; const float* wb_W; const float* wb_b;
  const float* wg_W; const float* wg_b; const float* wgm_W; const float* wgm_b;
  const float* rs_W; const float* rs_b; const float* ws_W; const float* ws_b;
  const float* out_b; float* out;
};

// 128 blocks = 16 batches x 8 slices, 512 threads.
__global__ __launch_bounds__(512) void ntm_coop(CoopP p) {
  cg::grid_group grid = cg::this_grid();
  __shared__ float mem[NN][MLD];
  __shared__ __attribute__((aligned(16))) float zh_s[KTOT];
  __shared__ __attribute__((aligned(16))) float h_loc[HCC];
  __shared__ __attribute__((aligned(16))) float rv_loc[HH * MM];
  __shared__ float gpart[128][5];
  __shared__ float hpart[128][5];
  __shared__ float opart[32][17];
  __shared__ float rk_s[HH][MM], wk_s[HH][MM], ev_s[HH][MM], av_s[HH][MM];
  __shared__ float rw_s[HH][NN], ww_s[HH][NN];
  __shared__ float memnorm[NN];
  __shared__ float wavescr[8][NN];
  __shared__ float scal_s[6][HH];
  __shared__ float shiftr[2][HH][3];
  __shared__ float c_loc[32];

  const int tid  = threadIdx.x;
  const int bid  = blockIdx.x;
  const int s    = bid & 7;
  const int b    = bid >> 3;
  const int lane = tid & 63;
  const int wv   = tid >> 6;

  // hoisted per-thread constants
  float biasg[4];
  if (tid < 32) {
    #pragma unroll
    for (int g = 0; g < 4; ++g) {
      int i = g * 256 + s * 32 + tid;
      biasg[g] = p.b_ih[i] + p.b_hh[i];
    }
  }
  float bias_vh = 0.0f;
  if (tid < 128) {
    int oh = s * 128 + tid;
    int a = oh >> 8, hh = (oh >> 6) & 3, m = oh & 63;
    const float* bb = (a == 0) ? p.rk_b : (a == 1) ? p.wk_b : (a == 2) ? p.er_b : p.ad_b;
    bias_vh = bb[hh * MM + m];
  }
  const float outb = (tid < 32) ? p.out_b[s * 32 + tid] : 0.0f;

  // init
  for (int i = tid; i < NN * MM; i += 512) mem[i >> 6][i & 63] = p.mem0[i];
  if (tid < 32) c_loc[tid] = 0.0f;
  if (tid < HH * MM) rv_loc[tid] = 0.0f;
  { rw_s[tid >> 7][tid & 127] = 0.0f; ww_s[tid >> 7][tid & 127] = 0.0f; }
  if (tid < 32) p.hbuf[(size_t)b * 256 + s * 32 + tid] = 0.0f;   // hbuf[0]
  grid.sync();

  const int* __restrict__ xrow = p.x + b * SS;
  const float4* __restrict__ Wg4 = (const float4*)p.Wg + (size_t)s * 160 * 128;
  const float4* __restrict__ Wh4 = (const float4*)p.Wh + (size_t)s * 64 * 128;
  const float4* __restrict__ Wo4 = (const float4*)p.Wo + (size_t)s * 128 * 32;

  for (int t = 0; t < SS; ++t) {
    const int pr = t & 1, cu = pr ^ 1;

    // ---- phase 1a: build zh = [emb, rv, h_prev] ----
    {
      const float* hprev = p.hbuf + (size_t)pr * 16 * 256 + b * 256;
      const int xbt = xrow[t];
      for (int k = tid; k < KTOT; k += 512) {
        float v;
        if (k < IND)      v = p.emb[(size_t)xbt * IND + k];
        else if (k < ZD)  v = rv_loc[k - IND];
        else              v = hprev[k - ZD];
        zh_s[k] = v;
      }
    }
    __syncthreads();

    // ---- phase 1b: gates slice partials (128 rows x 4-way split-K) ----
    {
      const int li = tid & 127, q = tid >> 7;   // q in [0,4)
      const float4* zh4 = (const float4*)zh_s;
      const int k40 = q * 40;
      float acc = 0.0f;
      #pragma unroll 8
      for (int kk = 0; kk < 40; ++kk) {
        float4 w = Wg4[(size_t)(k40 + kk) * 128 + li];
        float4 z = zh4[k40 + kk];
        acc += w.x * z.x + w.y * z.y + w.z * z.z + w.w * z.w;
      }
      gpart[li][q] = acc;
    }
    __syncthreads();

    // ---- phase 1c: reduce + LSTM + write h slice ----
    if (tid < 32) {
      float gv[4];
      #pragma unroll
      for (int g = 0; g < 4; ++g) {
        int li = g * 32 + tid;
        gv[g] = gpart[li][0] + gpart[li][1] + gpart[li][2] + gpart[li][3] + biasg[g];
      }
      float cn = sigm(gv[1]) * c_loc[tid] + sigm(gv[0]) * tanhf(gv[2]);
      c_loc[tid] = cn;
      float hv = sigm(gv[3]) * tanhf(cn);
      p.hbuf[(size_t)cu * 16 * 256 + b * 256 + s * 32 + tid] = hv;
    }
    grid.sync();   // SYNC A: full h ready

    // ---- phase 2: copy full h local ----
    if (tid < HCC) h_loc[tid] = p.hbuf[(size_t)cu * 16 * 256 + b * 256 + tid];
    __syncthreads();

    // vec-head slice partials (128 outs x 4-way split-K over 256)
    {
      const int li = tid & 127, q = tid >> 7;
      const float4* h4 = (const float4*)h_loc;
      const int c40 = q * 16;
      float acc = 0.0f;
      #pragma unroll 8
      for (int cc = 0; cc < 16; ++cc) {
        float4 w = Wh4[(size_t)(c40 + cc) * 128 + li];
        float4 h = h4[c40 + cc];
        acc += w.x * h.x + w.y * h.y + w.z * h.z + w.w * h.w;
      }
      hpart[li][q] = acc;
    }
    // out h-part partials (32 outs x 16-way split-K over 256)
    {
      const int lo = tid & 31, q = tid >> 5;    // q in [0,16)
      const float4* h4 = (const float4*)h_loc;
      float acc = 0.0f;
      #pragma unroll
      for (int kk = 0; kk < 4; ++kk) {
        int k4 = q * 4 + kk;
        float4 w = Wo4[(size_t)k4 * 32 + lo];
        float4 h = h4[k4];
        acc += w.x * h.x + w.y * h.y + w.z * h.z + w.w * h.w;
      }
      opart[lo][q] = acc;
    }
    // 6 scalar/shift dots for this slice (waves 0..5)
    if (wv < 6) {
      const int d = s * 6 + wv;
      float partial = 0.0f;
      if (d < 24) {
        const int pp = d >> 2, h2 = d & 3;
        const float* W2 = (pp == 0) ? p.rb_W : (pp == 1) ? p.rg_W : (pp == 2) ? p.rgm_W
                        : (pp == 3) ? p.wb_W : (pp == 4) ? p.wg_W : p.wgm_W;
        #pragma unroll
        for (int qq = 0; qq < 4; ++qq)
          partial += h_loc[qq * 64 + lane] * W2[h2 * HCC + qq * 64 + lane];
        #pragma unroll
        for (int dd = 1; dd < 64; dd <<= 1) partial += __shfl_xor(partial, dd, 64);
        if (lane == 0) {
          const float* b2 = (pp == 0) ? p.rb_b : (pp == 1) ? p.rg_b : (pp == 2) ? p.rgm_b
                          : (pp == 3) ? p.wb_b : (pp == 4) ? p.wg_b : p.wgm_b;
          float a2 = partial + b2[h2];
          float r;
          if (pp == 1 || pp == 4) r = sigm(a2);
          else { r = softplus_f(a2); if (pp == 2 || pp == 5) r += 1.0f; }
          p.scalg[b * 24 + pp * 4 + h2] = r;
        }
      } else {
        const int q2 = d - 24, pre = q2 / 12, rr = q2 % 12, h2 = rr / 3, jj = rr % 3;
        const float* W2 = pre ? p.ws_W : p.rs_W;
        #pragma unroll
        for (int qq = 0; qq < 4; ++qq)
          partial += h_loc[qq * 64 + lane] * W2[(size_t)(h2 * HCC + qq * 64 + lane) * 3 + jj];
        #pragma unroll
        for (int dd = 1; dd < 64; dd <<= 1) partial += __shfl_xor(partial, dd, 64);
        if (lane == 0) {
          const float* b2 = pre ? p.ws_b : p.rs_b;
          p.shiftg[b * 24 + pre * 12 + h2 * 3 + jj] = partial + b2[h2 * 3 + jj];
        }
      }
    }
    __syncthreads();
    // vec-head finalize -> headv
    if (tid < 128) {
      int oh = s * 128 + tid;
      int a = oh >> 8;
      float acc = hpart[tid][0] + hpart[tid][1] + hpart[tid][2] + hpart[tid][3] + bias_vh;
      float v = (a == 2) ? sigm(acc) : (a == 3) ? tanhf(acc) : acc;
      p.headv[b * 1024 + oh] = v;
    }
    grid.sync();   // SYNC B: all head outputs ready

    // ---- phase 3: replicated addressing + rv + mem update + out finalize ----
    for (int oh = tid; oh < 1024; oh += 512) {
      float v = p.headv[b * 1024 + oh];
      int a = oh >> 8, hh2 = (oh >> 6) & 3, m = oh & 63;
      if (a == 0)      rk_s[hh2][m] = v;
      else if (a == 1) wk_s[hh2][m] = v;
      else if (a == 2) ev_s[hh2][m] = v;
      else             av_s[hh2][m] = v;
    }
    if (tid < 24) ((float*)scal_s)[tid] = p.scalg[b * 24 + tid];
    else if (tid < 48) ((float*)shiftr)[tid - 24] = p.shiftg[b * 24 + tid - 24];
    if (tid < NN) {
      float ss = 0.0f;
      #pragma unroll 8
      for (int m = 0; m < MM; ++m) { float v = mem[tid][m]; ss += v * v; }
      memnorm[tid] = fmaxf(sqrtf(ss), 1e-12f);
    }
    __syncthreads();

    // addressing: 8 waves = {read,write} x 4 heads
    {
      const int isW = wv >> 2, hh = wv & 3;
      const int l = lane;
      const float* kv = isW ? wk_s[hh] : rk_s[hh];
      float* prevw = isW ? ww_s[hh] : rw_s[hh];
      const float beta  = scal_s[isW ? 3 : 0][hh];
      const float g     = scal_s[isW ? 4 : 1][hh];
      const float gamma = scal_s[isW ? 5 : 2][hh];
      float kl = kv[l];
      float kn2 = kl * kl;
      #pragma unroll
      for (int d = 1; d < 64; d <<= 1) kn2 += __shfl_xor(kn2, d, 64);
      const float kn = fmaxf(sqrtf(kn2), 1e-12f);
      float s0 = 0.0f, s1 = 0.0f;
      #pragma unroll 4
      for (int m = 0; m < MM; ++m) {
        float km = kv[m];
        s0 += mem[l][m] * km;
        s1 += mem[l + 64][m] * km;
      }
      float v0 = beta * (s0 / (memnorm[l] * kn));
      float v1 = beta * (s1 / (memnorm[l + 64] * kn));
      float mx = fmaxf(v0, v1);
      #pragma unroll
      for (int d = 1; d < 64; d <<= 1) mx = fmaxf(mx, __shfl_xor(mx, d, 64));
      float e0 = expf(v0 - mx), e1 = expf(v1 - mx);
      float sm = e0 + e1;
      #pragma unroll
      for (int d = 1; d < 64; d <<= 1) sm += __shfl_xor(sm, d, 64);
      const float inv = 1.0f / sm;
      float wg0 = g * (e0 * inv) + (1.0f - g) * prevw[l];
      float wg1 = g * (e1 * inv) + (1.0f - g) * prevw[l + 64];
      wavescr[wv][l] = wg0;
      wavescr[wv][l + 64] = wg1;
      float sh0 = shiftr[isW][hh][0], sh1 = shiftr[isW][hh][1], sh2 = shiftr[isW][hh][2];
      float shm = fmaxf(sh0, fmaxf(sh1, sh2));
      float es0 = expf(sh0 - shm), es1 = expf(sh1 - shm), es2 = expf(sh2 - shm);
      float esum = es0 + es1 + es2;
      es0 /= esum; es1 /= esum; es2 /= esum;
      float w_0 = es0 * wavescr[wv][(l + 1) & 127] + es1 * wavescr[wv][l]
                + es2 * wavescr[wv][(l + 127) & 127];
      const int n1 = l + 64;
      float w_1 = es0 * wavescr[wv][(n1 + 1) & 127] + es1 * wavescr[wv][n1]
                + es2 * wavescr[wv][(n1 + 127) & 127];
      float p0 = powf(w_0, gamma), p1 = powf(w_1, gamma);
      float tot = p0 + p1;
      #pragma unroll
      for (int d = 1; d < 64; d <<= 1) tot += __shfl_xor(tot, d, 64);
      const float invt = 1.0f / tot;
      prevw[l] = p0 * invt;
      prevw[l + 64] = p1 * invt;
    }
    __syncthreads();

    // rv = rw . mem (OLD mem)
    if (tid < HH * MM) {
      const int hh2 = tid >> 6, m = tid & 63;
      float acc = 0.0f;
      #pragma unroll 4
      for (int n = 0; n < NN; ++n) acc += rw_s[hh2][n] * mem[n][m];
      rv_loc[tid] = acc;
    }
    __syncthreads();

    // mem erase+add (replicated) + out rv-part partials
    {
      const int n = tid >> 2, m0 = (tid & 3) * 16;
      const float w0 = ww_s[0][n], w1 = ww_s[1][n], w2 = ww_s[2][n], w3 = ww_s[3][n];
      #pragma unroll
      for (int m = m0; m < m0 + 16; ++m) {
        float e  = w0 * ev_s[0][m] + w1 * ev_s[1][m] + w2 * ev_s[2][m] + w3 * ev_s[3][m];
        float aa = w0 * av_s[0][m] + w1 * av_s[1][m] + w2 * av_s[2][m] + w3 * av_s[3][m];
        mem[n][m] = mem[n][m] * (1.0f - e) + aa;
      }
      const int lo = tid & 31, q = tid >> 5;
      const float4* rv4 = (const float4*)rv_loc;
      float acc = 0.0f;
      #pragma unroll
      for (int kk = 0; kk < 4; ++kk) {
        int k4 = 64 + q * 4 + kk;
        float4 w = Wo4[(size_t)k4 * 32 + lo];
        float4 r = rv4[k4 - 64];
        acc += w.x * r.x + w.y * r.y + w.z * r.z + w.w * r.w;
      }
      opart[lo][q] += acc;
    }
    __syncthreads();

    // final logits for this o-slice
    if (tid < 32) {
      float r = outb;
      #pragma unroll
      for (int q = 0; q < 16; ++q) r += opart[tid][q];
      p.out[((size_t)b * SS + t) * OUTD + s * 32 + tid] = r;
    }
  }
}

// ====================== fallback paths (R7) ======================
struct Params {
  const int*   x;
  const float* emb;
  const float* mem0;
  const float* wih; int wih_sI, wih_sK;
  const float* whh; int whh_sI, whh_sK;
  const float* b_ih; const float* b_hh;
  const float* rk_W; const float* rk_b;
  const float* rb_W; const float* rb_b;
  const float* rg_W; const float* rg_b;
  const float* rs_W; const float* rs_b;
  const float* rgm_W; const float* rgm_b;
  const float* wk_W; const float* wk_b;
  const float* wb_W; const float* wb_b;
  const float* wg_W; const float* wg_b;
  const float* ws_W; const float* ws_b;
  const float* wgm_W; const float* wgm_b;
  const float* er_W; const float* er_b;
  const float* ad_W; const float* ad_b;
  const float* outW; int outW_sK, outW_sO;
  const float* out_b;
  float* out;
};

__global__ __launch_bounds__(256) void transpose_k(const float* __restrict__ src,
                                                   float* __restrict__ dst,
                                                   int R, int C) {
  __shared__ float tile[32][33];
  const int bx = blockIdx.x * 32;
  const int by = blockIdx.y * 32;
  const int tx = threadIdx.x, ty = threadIdx.y;
  for (int i = ty; i < 32; i += 8) {
    int r = by + i, c = bx + tx;
    if (r < R && c < C) tile[i][tx] = src[(size_t)r * C + c];
  }
  __syncthreads();
  for (int i = ty; i < 32; i += 8) {
    int c = bx + i, r = by + tx;
    if (c < C && r < R) dst[(size_t)c * R + r] = tile[tx][i];
  }
}

__global__ __launch_bounds__(1024) void ntm_generic(Params p) {
  __shared__ float mem[NN][MLD];
  __shared__ __attribute__((aligned(16))) float h_s[HCC];
  __shared__ float c_s[HCC];
  __shared__ __attribute__((aligned(16))) float z_s[ZD];
  __shared__ float gates_s[G4];
  __shared__ float rv_s[HH * MM];
  __shared__ float rw_s[HH][NN];
  __shared__ float ww_s[HH][NN];
  __shared__ float rk_s[HH][MM];
  __shared__ float wk_s[HH][MM];
  __shared__ float ev_s[HH][MM];
  __shared__ float av_s[HH][MM];
  __shared__ float scal_s[6][HH];
  __shared__ float shift_s[2][HH][3];
  __shared__ float memnorm[NN];
  __shared__ float wavescr[8][NN];
  __shared__ float part_s[6][OUTD];

  const int b = blockIdx.x;
  const int tid = threadIdx.x;

  for (int i = tid; i < NN * MM; i += 1024) mem[i >> 6][i & 63] = p.mem0[i];
  if (tid < HCC) { h_s[tid] = 0.0f; c_s[tid] = 0.0f; }
  if (tid < HH * NN) { rw_s[tid >> 7][tid & 127] = 0.0f; ww_s[tid >> 7][tid & 127] = 0.0f; }
  if (tid < HH * MM) rv_s[tid] = 0.0f;
  __syncthreads();

  for (int t = 0; t < SS; ++t) {
    if (tid < NN) {
      float s = 0.0f;
      #pragma unroll 8
      for (int m = 0; m < MM; ++m) { float v = mem[tid][m]; s += v * v; }
      memnorm[tid] = fmaxf(sqrtf(s), 1e-12f);
    } else if (tid < NN + ZD) {
      int k = tid - NN;
      if (k < IND) {
        int xbt = p.x[b * SS + t];
        z_s[k] = p.emb[(size_t)xbt * IND + k];
      } else {
        z_s[k] = rv_s[k - IND];
      }
    }
    __syncthreads();

    {
      const int i = tid;
      float acc = p.b_ih[i] + p.b_hh[i];
      {
        const float* wp = p.wih + (size_t)i * p.wih_sI;
        const int sK = p.wih_sK;
        #pragma unroll 4
        for (int j = 0; j < ZD / 4; ++j) {
          const float* w4 = wp + (size_t)(4 * j) * sK;
          acc += w4[0] * z_s[4 * j] + w4[sK] * z_s[4 * j + 1]
               + w4[2 * sK] * z_s[4 * j + 2] + w4[3 * sK] * z_s[4 * j + 3];
        }
      }
      {
        const float* wp = p.whh + (size_t)i * p.whh_sI;
        const int sK = p.whh_sK;
        #pragma unroll 4
        for (int j = 0; j < HCC / 4; ++j) {
          const float* w4 = wp + (size_t)(4 * j) * sK;
          acc += w4[0] * h_s[4 * j] + w4[sK] * h_s[4 * j + 1]
               + w4[2 * sK] * h_s[4 * j + 2] + w4[3 * sK] * h_s[4 * j + 3];
        }
      }
      gates_s[i] = acc;
    }
    __syncthreads();

    if (tid < HCC) {
      float gi = gates_s[tid], gf = gates_s[HCC + tid];
      float gg = gates_s[2 * HCC + tid], go = gates_s[3 * HCC + tid];
      float cn = sigm(gf) * c_s[tid] + sigm(gi) * tanhf(gg);
      c_s[tid] = cn;
      h_s[tid] = sigm(go) * tanhf(cn);
    }
    __syncthreads();

    {
      const int a = tid >> 8, idx = tid & 255, hh = idx >> 6, m = idx & 63;
      const float* W; const float* bb;
      if (a == 0)      { W = p.rk_W; bb = p.rk_b; }
      else if (a == 1) { W = p.wk_W; bb = p.wk_b; }
      else if (a == 2) { W = p.er_W; bb = p.er_b; }
      else             { W = p.ad_W; bb = p.ad_b; }
      const float* Wp = W + (size_t)(hh * HCC) * MM + m;
      float acc = bb[hh * MM + m];
      #pragma unroll 4
      for (int j = 0; j < HCC / 4; ++j) {
        const float* w4 = Wp + (size_t)(4 * j) * MM;
        acc += w4[0] * h_s[4 * j] + w4[MM] * h_s[4 * j + 1]
             + w4[2 * MM] * h_s[4 * j + 2] + w4[3 * MM] * h_s[4 * j + 3];
      }
      if (a == 0)      rk_s[hh][m] = acc;
      else if (a == 1) wk_s[hh][m] = acc;
      else if (a == 2) ev_s[hh][m] = sigm(acc);
      else             av_s[hh][m] = tanhf(acc);

      if (tid < 48) {
        if (tid < 24) {
          int pp = tid >> 2, h2 = tid & 3;
          const float* W2; const float* b2;
          switch (pp) {
            case 0:  W2 = p.rb_W;  b2 = p.rb_b;  break;
            case 1:  W2 = p.rg_W;  b2 = p.rg_b;  break;
            case 2:  W2 = p.rgm_W; b2 = p.rgm_b; break;
            case 3:  W2 = p.wb_W;  b2 = p.wb_b;  break;
            case 4:  W2 = p.wg_W;  b2 = p.wg_b;  break;
            default: W2 = p.wgm_W; b2 = p.wgm_b; break;
          }
          float acc2 = b2[h2];
          const float* w2 = W2 + (size_t)h2 * HCC;
          #pragma unroll 4
          for (int c = 0; c < HCC; ++c) acc2 += h_s[c] * w2[c];
          float r;
          if (pp == 1 || pp == 4) r = sigm(acc2);
          else { r = softplus_f(acc2); if (pp == 2 || pp == 5) r += 1.0f; }
          scal_s[pp][h2] = r;
        } else {
          int q = tid - 24, pre = q / 12, rr = q % 12, h2 = rr / 3, j = rr % 3;
          const float* W2 = pre ? p.ws_W : p.rs_W;
          const float* b2 = pre ? p.ws_b : p.rs_b;
          float acc2 = b2[h2 * 3 + j];
          const float* w2 = W2 + (size_t)(h2 * HCC) * 3 + j;
          #pragma unroll 4
          for (int c = 0; c < HCC; ++c) acc2 += h_s[c] * w2[(size_t)c * 3];
          shift_s[pre][h2][j] = acc2;
        }
      }
    }
    __syncthreads();

    {
      const int w = tid >> 6, l = tid & 63;
      if (w < 8) {
        const int isW = w >> 2, hh = w & 3;
        const float* kv = isW ? wk_s[hh] : rk_s[hh];
        float* prevw = isW ? ww_s[hh] : rw_s[hh];
        const float beta  = scal_s[isW ? 3 : 0][hh];
        const float g     = scal_s[isW ? 4 : 1][hh];
        const float gamma = scal_s[isW ? 5 : 2][hh];
        float kl = kv[l];
        float kn2 = kl * kl;
        #pragma unroll
        for (int d = 1; d < 64; d <<= 1) kn2 += __shfl_xor(kn2, d, 64);
        const float kn = fmaxf(sqrtf(kn2), 1e-12f);
        float s0 = 0.0f, s1 = 0.0f;
        #pragma unroll 4
        for (int m = 0; m < MM; ++m) {
          float km = kv[m];
          s0 += mem[l][m] * km;
          s1 += mem[l + 64][m] * km;
        }
        float v0 = beta * (s0 / (memnorm[l] * kn));
        float v1 = beta * (s1 / (memnorm[l + 64] * kn));
        float mx = fmaxf(v0, v1);
        #pragma unroll
        for (int d = 1; d < 64; d <<= 1) mx = fmaxf(mx, __shfl_xor(mx, d, 64));
        float e0 = expf(v0 - mx), e1 = expf(v1 - mx);
        float sm = e0 + e1;
        #pragma unroll
        for (int d = 1; d < 64; d <<= 1) sm += __shfl_xor(sm, d, 64);
        const float inv = 1.0f / sm;
        float wg0 = g * (e0 * inv) + (1.0f - g) * prevw[l];
        float wg1 = g * (e1 * inv) + (1.0f - g) * prevw[l + 64];
        wavescr[w][l] = wg0;
        wavescr[w][l + 64] = wg1;
        float sh0 = shift_s[isW][hh][0], sh1 = shift_s[isW][hh][1], sh2 = shift_s[isW][hh][2];
        float shm = fmaxf(sh0, fmaxf(sh1, sh2));
        float es0 = expf(sh0 - shm), es1 = expf(sh1 - shm), es2 = expf(sh2 - shm);
        float esum = es0 + es1 + es2;
        es0 /= esum; es1 /= esum; es2 /= esum;
        float w_0 = es0 * wavescr[w][(l + 1) & 127] + es1 * wavescr[w][l]
                  + es2 * wavescr[w][(l + 127) & 127];
        const int n1 = l + 64;
        float w_1 = es0 * wavescr[w][(n1 + 1) & 127] + es1 * wavescr[w][n1]
                  + es2 * wavescr[w][(n1 + 127) & 127];
        float p0 = powf(w_0, gamma), p1 = powf(w_1, gamma);
        float tot = p0 + p1;
        #pragma unroll
        for (int d = 1; d < 64; d <<= 1) tot += __shfl_xor(tot, d, 64);
        const float invt = 1.0f / tot;
        prevw[l] = p0 * invt;
        prevw[l + 64] = p1 * invt;
      } else {
        const int o = tid & 255, hf = (tid - 512) >> 8;
        const float* Wp = p.outW + (size_t)o * p.outW_sO + (size_t)(hf * 128) * p.outW_sK;
        const int sK = p.outW_sK;
        float acc = 0.0f;
        const float* hp = h_s + hf * 128;
        #pragma unroll 4
        for (int k = 0; k < 128; ++k) acc += hp[k] * Wp[(size_t)k * sK];
        part_s[hf][o] = acc;
      }
    }
    __syncthreads();

    if (tid < HH * MM) {
      const int hh = tid >> 6, m = tid & 63;
      float acc = 0.0f;
      #pragma unroll 4
      for (int n = 0; n < NN; ++n) acc += rw_s[hh][n] * mem[n][m];
      rv_s[tid] = acc;
    }
    __syncthreads();

    {
      const int n = tid >> 3, j = tid & 7, m0 = j * 8;
      const float w0 = ww_s[0][n], w1 = ww_s[1][n], w2 = ww_s[2][n], w3 = ww_s[3][n];
      #pragma unroll
      for (int m = m0; m < m0 + 8; ++m) {
        float e  = w0 * ev_s[0][m] + w1 * ev_s[1][m] + w2 * ev_s[2][m] + w3 * ev_s[3][m];
        float aa = w0 * av_s[0][m] + w1 * av_s[1][m] + w2 * av_s[2][m] + w3 * av_s[3][m];
        mem[n][m] = mem[n][m] * (1.0f - e) + aa;
      }
      const int o = tid & 255, hf = tid >> 8;
      const float* Wp = p.outW + (size_t)o * p.outW_sO + (size_t)(HCC + hf * 64) * p.outW_sK;
      const int sK = p.outW_sK;
      float acc = 0.0f;
      const float* rvp = rv_s + hf * 64;
      #pragma unroll 4
      for (int k = 0; k < 64; ++k) acc += rvp[k] * Wp[(size_t)k * sK];
      part_s[2 + hf][o] = acc;
    }
    __syncthreads();

    if (tid < OUTD) {
      float r = part_s[0][tid] + part_s[1][tid] + part_s[2][tid]
              + part_s[3][tid] + part_s[4][tid] + part_s[5][tid] + p.out_b[tid];
      p.out[((size_t)b * SS + t) * OUTD + tid] = r;
    }
    __syncthreads();
  }
}

extern "C" void kernel_launch(void* const* d_in, const int* in_sizes, int n_in,
                              void* d_out, int out_size, void* d_ws, size_t ws_size,
                              hipStream_t stream) {
  const int*   x     = (const int*)d_in[0];
  const float* emb   = (const float*)d_in[1];
  const float* mem0  = (const float*)d_in[2];
  const float* w_ih  = (const float*)d_in[3];
  const float* w_hh  = (const float*)d_in[4];
  const float* b_ih  = (const float*)d_in[5];
  const float* b_hh  = (const float*)d_in[6];
  const float* rk_W  = (const float*)d_in[7];
  const float* rk_b  = (const float*)d_in[8];
  const float* rb_W  = (const float*)d_in[9];
  const float* rb_b  = (const float*)d_in[10];
  const float* rg_W  = (const float*)d_in[11];
  const float* rg_b  = (const float*)d_in[12];
  const float* rs_W  = (const float*)d_in[13];
  const float* rs_b  = (const float*)d_in[14];
  const float* rgm_W = (const float*)d_in[15];
  const float* rgm_b = (const float*)d_in[16];
  const float* wk_W  = (const float*)d_in[17];
  const float* wk_b  = (const float*)d_in[18];
  const float* wb_W  = (const float*)d_in[19];
  const float* wb_b  = (const float*)d_in[20];
  const float* wg_W  = (const float*)d_in[21];
  const float* wg_b  = (const float*)d_in[22];
  const float* ws_W  = (const float*)d_in[23];
  const float* ws_b  = (const float*)d_in[24];
  const float* wgm_W = (const float*)d_in[25];
  const float* wgm_b = (const float*)d_in[26];
  const float* er_W  = (const float*)d_in[27];
  const float* er_b  = (const float*)d_in[28];
  const float* ad_W  = (const float*)d_in[29];
  const float* ad_b  = (const float*)d_in[30];
  const float* out_W = (const float*)d_in[31];
  const float* out_b = (const float*)d_in[32];
  float* out = (float*)d_out;

  const size_t needCoop = (size_t)NCOOP * sizeof(float);

  if (ws_size >= needCoop) {
    float* ws = (float*)d_ws;
    float* Wg = ws;
    float* Wh = Wg + NWG;
    float* Wo = Wh + NWH;
    float* hb = Wo + NWO;
    float* hv = hb + NHB;
    float* sg = hv + NHV;
    float* sh = sg + NSC;
    prep_g<<<dim3((NWG + 255) / 256), dim3(256), 0, stream>>>(w_ih, w_hh, Wg);
    prep_h<<<dim3((NWH + 255) / 256), dim3(256), 0, stream>>>(rk_W, wk_W, er_W, ad_W, Wh);
    prep_o<<<dim3((NWO + 255) / 256), dim3(256), 0, stream>>>(out_W, Wo);

    CoopP cp{};
    cp.x = x; cp.emb = emb; cp.mem0 = mem0;
    cp.Wg = Wg; cp.Wh = Wh; cp.Wo = Wo;
    cp.hbuf = hb; cp.headv = hv; cp.scalg = sg; cp.shiftg = sh;
    cp.b_ih = b_ih; cp.b_hh = b_hh;
    cp.rk_b = rk_b; cp.wk_b = wk_b; cp.er_b = er_b; cp.ad_b = ad_b;
    cp.rb_W = rb_W; cp.rb_b = rb_b; cp.rg_W = rg_W; cp.rg_b = rg_b;
    cp.rgm_W = rgm_W; cp.rgm_b = rgm_b; cp.wb_W = wb_W; cp.wb_b = wb_b;
    cp.wg_W = wg_W; cp.wg_b = wg_b; cp.wgm_W = wgm_W; cp.wgm_b = wgm_b;
    cp.rs_W = rs_W; cp.rs_b = rs_b; cp.ws_W = ws_W; cp.ws_b = ws_b;
    cp.out_b = out_b; cp.out = out;

    void* args[] = { &cp };
    hipLaunchCooperativeKernel((const void*)ntm_coop, dim3(BB * 8), dim3(512),
                               args, 0, stream);
  } else {
    Params p{};
    p.x = x; p.emb = emb; p.mem0 = mem0;
    p.b_ih = b_ih; p.b_hh = b_hh;
    p.rk_W = rk_W; p.rk_b = rk_b; p.rb_W = rb_W; p.rb_b = rb_b;
    p.rg_W = rg_W; p.rg_b = rg_b; p.rs_W = rs_W; p.rs_b = rs_b;
    p.rgm_W = rgm_W; p.rgm_b = rgm_b;
    p.wk_W = wk_W; p.wk_b = wk_b; p.wb_W = wb_W; p.wb_b = wb_b;
    p.wg_W = wg_W; p.wg_b = wg_b; p.ws_W = ws_W; p.ws_b = ws_b;
    p.wgm_W = wgm_W; p.wgm_b = wgm_b;
    p.er_W = er_W; p.er_b = er_b; p.ad_W = ad_W; p.ad_b = ad_b;
    p.out_b = out_b; p.out = out;

    const size_t nWih  = (size_t)ZD * G4;
    const size_t nWhh  = (size_t)HCC * G4;
    const size_t nWout = (size_t)512 * OUTD;
    const size_t needT = (nWih + nWhh + nWout) * sizeof(float);
    float* ws = (float*)d_ws;

    if (ws_size >= needT) {
      dim3 blk(32, 8);
      transpose_k<<<dim3(ZD / 32, G4 / 32), blk, 0, stream>>>(w_ih, ws, G4, ZD);
      transpose_k<<<dim3(HCC / 32, G4 / 32), blk, 0, stream>>>(w_hh, ws + nWih, G4, HCC);
      transpose_k<<<dim3(512 / 32, OUTD / 32), blk, 0, stream>>>(out_W, ws + nWih + nWhh, OUTD, 512);
      p.wih = ws;                p.wih_sI = 1;   p.wih_sK = G4;
      p.whh = ws + nWih;         p.whh_sI = 1;   p.whh_sK = G4;
      p.outW = ws + nWih + nWhh; p.outW_sK = OUTD; p.outW_sO = 1;
    } else {
      p.wih = w_ih;  p.wih_sI = ZD;  p.wih_sK = 1;
      p.whh = w_hh;  p.whh_sI = HCC; p.whh_sK = 1;
      p.outW = out_W; p.outW_sK = 1; p.outW_sO = 512;
    }
    ntm_generic<<<dim3(BB), dim3(1024), 0, stream>>>(p);
  }
}

// Round 9
// 6745.844 us; speedup vs baseline: 10.1156x; 1.7734x over previous
//
#include <hip/hip_runtime.h>
#include <cstdint>
#include <cstddef>

#define BB   16
#define SS   256
#define IND  128
#define OUTD 256
#define HCC  256
#define G4   1024   // 4*HC
#define ZD   384    // IND + H*M
#define KTOT 640    // ZD + HCC
#define NN   128
#define MM   64
#define HH   4
#define MLD  65

__device__ __forceinline__ float sigm(float x) { return 1.0f / (1.0f + expf(-x)); }
__device__ __forceinline__ float softplus_f(float x) {
  return fmaxf(x, 0.0f) + log1pf(expf(-fabsf(x)));
}

// ====================== cooperative-style path (custom barriers) ======================
// ws float layout:
//  Wg4 [8][160][128][4]   655360   gates slice-major float4 layout
//  Wh4 [8][64][128][4]    262144   vec-head slices
//  Wo4 [8][128][32][4]    131072   out slices (full 512 depth)
//  hbuf[2][16][256]         8192
//  headv[16][1024]         16384
//  scalg[16][24]             384
//  shiftg[16][24]            384
//  bar  [16*32 uints]        512   per-batch barrier counters (128B apart)
#define NWG 655360
#define NWH 262144
#define NWO 131072
#define NHB 8192
#define NHV 16384
#define NSC 384
#define NSH 384
#define NBAR 512
#define NCOOP (NWG + NWH + NWO + NHB + NHV + NSC + NSH + NBAR)

__global__ __launch_bounds__(256) void prep_g(const float* __restrict__ wih,
                                              const float* __restrict__ whh,
                                              float* __restrict__ dst) {
  int idx = blockIdx.x * 256 + threadIdx.x;
  if (idx >= NWG) return;
  int j  = idx & 3;
  int li = (idx >> 2) & 127;
  int r  = idx >> 9;              // s*160 + k4
  int k4 = r % 160, s = r / 160;
  int g  = li >> 5, jj = li & 31;
  int i  = g * 256 + s * 32 + jj;
  int k  = k4 * 4 + j;
  dst[idx] = (k < ZD) ? wih[(size_t)i * ZD + k] : whh[(size_t)i * HCC + (k - ZD)];
}

__global__ __launch_bounds__(256) void prep_h(const float* __restrict__ rkW,
                                              const float* __restrict__ wkW,
                                              const float* __restrict__ erW,
                                              const float* __restrict__ adW,
                                              float* __restrict__ dst) {
  int idx = blockIdx.x * 256 + threadIdx.x;
  if (idx >= NWH) return;
  int j  = idx & 3;
  int li = (idx >> 2) & 127;
  int r  = idx >> 9;              // s*64 + c4
  int c4 = r & 63, s = r >> 6;
  int oh = s * 128 + li;
  int a = oh >> 8, hh = (oh >> 6) & 3, m = oh & 63;
  int c = c4 * 4 + j;
  const float* W = (a == 0) ? rkW : (a == 1) ? wkW : (a == 2) ? erW : adW;
  dst[idx] = W[((size_t)hh * HCC + c) * MM + m];
}

__global__ __launch_bounds__(256) void prep_o(const float* __restrict__ outW,
                                              float* __restrict__ dst) {
  int idx = blockIdx.x * 256 + threadIdx.x;
  if (idx >= NWO) return;
  int j  = idx & 3;
  int lo = (idx >> 2) & 31;
  int r  = idx >> 7;              // s*128 + k4
  int k4 = r & 127, s = r >> 7;
  int o = s * 32 + lo;
  int k = k4 * 4 + j;
  dst[idx] = outW[(size_t)o * 512 + k];
}

__global__ __launch_bounds__(256) void zero_bar(unsigned* __restrict__ bar) {
  int idx = blockIdx.x * 256 + threadIdx.x;
  if (idx < NBAR) bar[idx] = 0u;
}

struct CoopP {
  const int* x; const float* emb; const float* mem0;
  const float* Wg; const float* Wh; const float* Wo;
  float* hbuf; float* headv; float* scalg; float* shiftg;
  unsigned* bar;
  const float* b_ih; const float* b_hh;
  const float* rk_b; const float* wk_b; const float* er_b; const float* ad_b;
  const float* rb_W; const float* rb_b; const float* rg_W; const float* rg_b;
  const float* rgm_W; const float* rgm_b; const float* wb_W; const float* wb_b;
  const float* wg_W; const float* wg_b; const float* wgm_W; const float* wgm_b;
  const float* rs_W; const float* rs_b; const float* ws_W; const float* ws_b;
  const float* out_b; float* out;
};

// 128 blocks = 16 batches x 8 slices, 512 threads. Per-batch 8-block barriers.
__global__ __launch_bounds__(512) void ntm_coop(CoopP p) {
  __shared__ float mem[NN][MLD];
  __shared__ __attribute__((aligned(16))) float zh_s[KTOT];
  __shared__ __attribute__((aligned(16))) float h_loc[HCC];
  __shared__ __attribute__((aligned(16))) float rv_loc[HH * MM];
  __shared__ float gpart[128][5];
  __shared__ float hpart[128][5];
  __shared__ float opart[32][17];
  __shared__ float rk_s[HH][MM], wk_s[HH][MM], ev_s[HH][MM], av_s[HH][MM];
  __shared__ float rw_s[HH][NN], ww_s[HH][NN];
  __shared__ float memnorm[NN];
  __shared__ float wavescr[8][NN];
  __shared__ float scal_s[6][HH];
  __shared__ float shiftr[2][HH][3];
  __shared__ float c_loc[32];

  const int tid  = threadIdx.x;
  const int bid  = blockIdx.x;
  const int s    = bid & 7;
  const int b    = bid >> 3;
  const int lane = tid & 63;
  const int wv   = tid >> 6;

  unsigned* __restrict__ mybar = p.bar + b * 32;
  unsigned bar_target = 0;

  // hoisted per-thread constants
  float biasg[4];
  if (tid < 32) {
    #pragma unroll
    for (int g = 0; g < 4; ++g) {
      int i = g * 256 + s * 32 + tid;
      biasg[g] = p.b_ih[i] + p.b_hh[i];
    }
  }
  float bias_vh = 0.0f;
  if (tid < 128) {
    int oh = s * 128 + tid;
    int a = oh >> 8, hh = (oh >> 6) & 3, m = oh & 63;
    const float* bb = (a == 0) ? p.rk_b : (a == 1) ? p.wk_b : (a == 2) ? p.er_b : p.ad_b;
    bias_vh = bb[hh * MM + m];
  }
  const float outb = (tid < 32) ? p.out_b[s * 32 + tid] : 0.0f;

  // init
  for (int i = tid; i < NN * MM; i += 512) mem[i >> 6][i & 63] = p.mem0[i];
  if (tid < 32) c_loc[tid] = 0.0f;
  if (tid < HH * MM) rv_loc[tid] = 0.0f;
  { rw_s[tid >> 7][tid & 127] = 0.0f; ww_s[tid >> 7][tid & 127] = 0.0f; }
  if (tid < 32) p.hbuf[(size_t)b * 256 + s * 32 + tid] = 0.0f;   // hbuf[0]

  // ---- per-batch barrier (8 blocks, monotonic counter) ----
  #define BATCH_BARRIER()                                                        \
    do {                                                                         \
      bar_target += 8;                                                           \
      __syncthreads();                                                           \
      if (tid == 0) {                                                            \
        __threadfence();                                                         \
        atomicAdd(mybar, 1u);                                                    \
        while (__hip_atomic_load(mybar, __ATOMIC_RELAXED,                        \
                                 __HIP_MEMORY_SCOPE_AGENT) < bar_target) {       \
          __builtin_amdgcn_s_sleep(2);                                           \
        }                                                                        \
        __threadfence();                                                         \
      }                                                                          \
      __syncthreads();                                                           \
    } while (0)

  BATCH_BARRIER();   // hbuf[0] visible to all 8 blocks of this batch

  const int* __restrict__ xrow = p.x + b * SS;
  const float4* __restrict__ Wg4 = (const float4*)p.Wg + (size_t)s * 160 * 128;
  const float4* __restrict__ Wh4 = (const float4*)p.Wh + (size_t)s * 64 * 128;
  const float4* __restrict__ Wo4 = (const float4*)p.Wo + (size_t)s * 128 * 32;

  for (int t = 0; t < SS; ++t) {
    const int pr = t & 1, cu = pr ^ 1;

    // ---- phase 1a: build zh = [emb, rv, h_prev] ----
    {
      const float* hprev = p.hbuf + (size_t)pr * 16 * 256 + b * 256;
      const int xbt = xrow[t];
      for (int k = tid; k < KTOT; k += 512) {
        float v;
        if (k < IND)      v = p.emb[(size_t)xbt * IND + k];
        else if (k < ZD)  v = rv_loc[k - IND];
        else              v = hprev[k - ZD];
        zh_s[k] = v;
      }
    }
    __syncthreads();

    // ---- phase 1b: gates slice partials (128 rows x 4-way split-K) ----
    {
      const int li = tid & 127, q = tid >> 7;   // q in [0,4)
      const float4* zh4 = (const float4*)zh_s;
      const int k40 = q * 40;
      float acc = 0.0f;
      #pragma unroll 8
      for (int kk = 0; kk < 40; ++kk) {
        float4 w = Wg4[(size_t)(k40 + kk) * 128 + li];
        float4 z = zh4[k40 + kk];
        acc += w.x * z.x + w.y * z.y + w.z * z.z + w.w * z.w;
      }
      gpart[li][q] = acc;
    }
    __syncthreads();

    // ---- phase 1c: reduce + LSTM + write h slice ----
    if (tid < 32) {
      float gv[4];
      #pragma unroll
      for (int g = 0; g < 4; ++g) {
        int li = g * 32 + tid;
        gv[g] = gpart[li][0] + gpart[li][1] + gpart[li][2] + gpart[li][3] + biasg[g];
      }
      float cn = sigm(gv[1]) * c_loc[tid] + sigm(gv[0]) * tanhf(gv[2]);
      c_loc[tid] = cn;
      float hv = sigm(gv[3]) * tanhf(cn);
      p.hbuf[(size_t)cu * 16 * 256 + b * 256 + s * 32 + tid] = hv;
    }
    BATCH_BARRIER();   // SYNC A: full h ready

    // ---- phase 2: copy full h local ----
    if (tid < HCC) h_loc[tid] = p.hbuf[(size_t)cu * 16 * 256 + b * 256 + tid];
    __syncthreads();

    // vec-head slice partials (128 outs x 4-way split-K over 256)
    {
      const int li = tid & 127, q = tid >> 7;
      const float4* h4 = (const float4*)h_loc;
      const int c40 = q * 16;
      float acc = 0.0f;
      #pragma unroll 8
      for (int cc = 0; cc < 16; ++cc) {
        float4 w = Wh4[(size_t)(c40 + cc) * 128 + li];
        float4 h = h4[c40 + cc];
        acc += w.x * h.x + w.y * h.y + w.z * h.z + w.w * h.w;
      }
      hpart[li][q] = acc;
    }
    // out h-part partials (32 outs x 16-way split-K over 256)
    {
      const int lo = tid & 31, q = tid >> 5;    // q in [0,16)
      const float4* h4 = (const float4*)h_loc;
      float acc = 0.0f;
      #pragma unroll
      for (int kk = 0; kk < 4; ++kk) {
        int k4 = q * 4 + kk;
        float4 w = Wo4[(size_t)k4 * 32 + lo];
        float4 h = h4[k4];
        acc += w.x * h.x + w.y * h.y + w.z * h.z + w.w * h.w;
      }
      opart[lo][q] = acc;
    }
    // 6 scalar/shift dots for this slice (waves 0..5)
    if (wv < 6) {
      const int d = s * 6 + wv;
      float partial = 0.0f;
      if (d < 24) {
        const int pp = d >> 2, h2 = d & 3;
        const float* W2 = (pp == 0) ? p.rb_W : (pp == 1) ? p.rg_W : (pp == 2) ? p.rgm_W
                        : (pp == 3) ? p.wb_W : (pp == 4) ? p.wg_W : p.wgm_W;
        #pragma unroll
        for (int qq = 0; qq < 4; ++qq)
          partial += h_loc[qq * 64 + lane] * W2[h2 * HCC + qq * 64 + lane];
        #pragma unroll
        for (int dd = 1; dd < 64; dd <<= 1) partial += __shfl_xor(partial, dd, 64);
        if (lane == 0) {
          const float* b2 = (pp == 0) ? p.rb_b : (pp == 1) ? p.rg_b : (pp == 2) ? p.rgm_b
                          : (pp == 3) ? p.wb_b : (pp == 4) ? p.wg_b : p.wgm_b;
          float a2 = partial + b2[h2];
          float r;
          if (pp == 1 || pp == 4) r = sigm(a2);
          else { r = softplus_f(a2); if (pp == 2 || pp == 5) r += 1.0f; }
          p.scalg[b * 24 + pp * 4 + h2] = r;
        }
      } else {
        const int q2 = d - 24, pre = q2 / 12, rr = q2 % 12, h2 = rr / 3, jj = rr % 3;
        const float* W2 = pre ? p.ws_W : p.rs_W;
        #pragma unroll
        for (int qq = 0; qq < 4; ++qq)
          partial += h_loc[qq * 64 + lane] * W2[(size_t)(h2 * HCC + qq * 64 + lane) * 3 + jj];
        #pragma unroll
        for (int dd = 1; dd < 64; dd <<= 1) partial += __shfl_xor(partial, dd, 64);
        if (lane == 0) {
          const float* b2 = pre ? p.ws_b : p.rs_b;
          p.shiftg[b * 24 + pre * 12 + h2 * 3 + jj] = partial + b2[h2 * 3 + jj];
        }
      }
    }
    __syncthreads();
    // vec-head finalize -> headv
    if (tid < 128) {
      int oh = s * 128 + tid;
      int a = oh >> 8;
      float acc = hpart[tid][0] + hpart[tid][1] + hpart[tid][2] + hpart[tid][3] + bias_vh;
      float v = (a == 2) ? sigm(acc) : (a == 3) ? tanhf(acc) : acc;
      p.headv[b * 1024 + oh] = v;
    }
    BATCH_BARRIER();   // SYNC B: all head outputs ready

    // ---- phase 3: replicated addressing + rv + mem update + out finalize ----
    for (int oh = tid; oh < 1024; oh += 512) {
      float v = p.headv[b * 1024 + oh];
      int a = oh >> 8, hh2 = (oh >> 6) & 3, m = oh & 63;
      if (a == 0)      rk_s[hh2][m] = v;
      else if (a == 1) wk_s[hh2][m] = v;
      else if (a == 2) ev_s[hh2][m] = v;
      else             av_s[hh2][m] = v;
    }
    if (tid < 24) ((float*)scal_s)[tid] = p.scalg[b * 24 + tid];
    else if (tid < 48) ((float*)shiftr)[tid - 24] = p.shiftg[b * 24 + tid - 24];
    if (tid < NN) {
      float ss = 0.0f;
      #pragma unroll 8
      for (int m = 0; m < MM; ++m) { float v = mem[tid][m]; ss += v * v; }
      memnorm[tid] = fmaxf(sqrtf(ss), 1e-12f);
    }
    __syncthreads();

    // addressing: 8 waves = {read,write} x 4 heads
    {
      const int isW = wv >> 2, hh = wv & 3;
      const int l = lane;
      const float* kv = isW ? wk_s[hh] : rk_s[hh];
      float* prevw = isW ? ww_s[hh] : rw_s[hh];
      const float beta  = scal_s[isW ? 3 : 0][hh];
      const float g     = scal_s[isW ? 4 : 1][hh];
      const float gamma = scal_s[isW ? 5 : 2][hh];
      float kl = kv[l];
      float kn2 = kl * kl;
      #pragma unroll
      for (int d = 1; d < 64; d <<= 1) kn2 += __shfl_xor(kn2, d, 64);
      const float kn = fmaxf(sqrtf(kn2), 1e-12f);
      float s0 = 0.0f, s1 = 0.0f;
      #pragma unroll 4
      for (int m = 0; m < MM; ++m) {
        float km = kv[m];
        s0 += mem[l][m] * km;
        s1 += mem[l + 64][m] * km;
      }
      float v0 = beta * (s0 / (memnorm[l] * kn));
      float v1 = beta * (s1 / (memnorm[l + 64] * kn));
      float mx = fmaxf(v0, v1);
      #pragma unroll
      for (int d = 1; d < 64; d <<= 1) mx = fmaxf(mx, __shfl_xor(mx, d, 64));
      float e0 = expf(v0 - mx), e1 = expf(v1 - mx);
      float sm = e0 + e1;
      #pragma unroll
      for (int d = 1; d < 64; d <<= 1) sm += __shfl_xor(sm, d, 64);
      const float inv = 1.0f / sm;
      float wg0 = g * (e0 * inv) + (1.0f - g) * prevw[l];
      float wg1 = g * (e1 * inv) + (1.0f - g) * prevw[l + 64];
      wavescr[wv][l] = wg0;
      wavescr[wv][l + 64] = wg1;
      float sh0 = shiftr[isW][hh][0], sh1 = shiftr[isW][hh][1], sh2 = shiftr[isW][hh][2];
      float shm = fmaxf(sh0, fmaxf(sh1, sh2));
      float es0 = expf(sh0 - shm), es1 = expf(sh1 - shm), es2 = expf(sh2 - shm);
      float esum = es0 + es1 + es2;
      es0 /= esum; es1 /= esum; es2 /= esum;
      float w_0 = es0 * wavescr[wv][(l + 1) & 127] + es1 * wavescr[wv][l]
                + es2 * wavescr[wv][(l + 127) & 127];
      const int n1 = l + 64;
      float w_1 = es0 * wavescr[wv][(n1 + 1) & 127] + es1 * wavescr[wv][n1]
                + es2 * wavescr[wv][(n1 + 127) & 127];
      float p0 = powf(w_0, gamma), p1 = powf(w_1, gamma);
      float tot = p0 + p1;
      #pragma unroll
      for (int d = 1; d < 64; d <<= 1) tot += __shfl_xor(tot, d, 64);
      const float invt = 1.0f / tot;
      prevw[l] = p0 * invt;
      prevw[l + 64] = p1 * invt;
    }
    __syncthreads();

    // rv = rw . mem (OLD mem)
    if (tid < HH * MM) {
      const int hh2 = tid >> 6, m = tid & 63;
      float acc = 0.0f;
      #pragma unroll 4
      for (int n = 0; n < NN; ++n) acc += rw_s[hh2][n] * mem[n][m];
      rv_loc[tid] = acc;
    }
    __syncthreads();

    // mem erase+add (replicated) + out rv-part partials
    {
      const int n = tid >> 2, m0 = (tid & 3) * 16;
      const float w0 = ww_s[0][n], w1 = ww_s[1][n], w2 = ww_s[2][n], w3 = ww_s[3][n];
      #pragma unroll
      for (int m = m0; m < m0 + 16; ++m) {
        float e  = w0 * ev_s[0][m] + w1 * ev_s[1][m] + w2 * ev_s[2][m] + w3 * ev_s[3][m];
        float aa = w0 * av_s[0][m] + w1 * av_s[1][m] + w2 * av_s[2][m] + w3 * av_s[3][m];
        mem[n][m] = mem[n][m] * (1.0f - e) + aa;
      }
      const int lo = tid & 31, q = tid >> 5;
      const float4* rv4 = (const float4*)rv_loc;
      float acc = 0.0f;
      #pragma unroll
      for (int kk = 0; kk < 4; ++kk) {
        int k4 = 64 + q * 4 + kk;
        float4 w = Wo4[(size_t)k4 * 32 + lo];
        float4 r = rv4[k4 - 64];
        acc += w.x * r.x + w.y * r.y + w.z * r.z + w.w * r.w;
      }
      opart[lo][q] += acc;
    }
    __syncthreads();

    // final logits for this o-slice
    if (tid < 32) {
      float r = outb;
      #pragma unroll
      for (int q = 0; q < 16; ++q) r += opart[tid][q];
      p.out[((size_t)b * SS + t) * OUTD + s * 32 + tid] = r;
    }
  }
  #undef BATCH_BARRIER
}

// ====================== fallback paths ======================
struct Params {
  const int*   x;
  const float* emb;
  const float* mem0;
  const float* wih; int wih_sI, wih_sK;
  const float* whh; int whh_sI, whh_sK;
  const float* b_ih; const float* b_hh;
  const float* rk_W; const float* rk_b;
  const float* rb_W; const float* rb_b;
  const float* rg_W; const float* rg_b;
  const float* rs_W; const float* rs_b;
  const float* rgm_W; const float* rgm_b;
  const float* wk_W; const float* wk_b;
  const float* wb_W; const float* wb_b;
  const float* wg_W; const float* wg_b;
  const float* ws_W; const float* ws_b;
  const float* wgm_W; const float* wgm_b;
  const float* er_W; const float* er_b;
  const float* ad_W; const float* ad_b;
  const float* outW; int outW_sK, outW_sO;
  const float* out_b;
  float* out;
};

__global__ __launch_bounds__(256) void transpose_k(const float* __restrict__ src,
                                                   float* __restrict__ dst,
                                                   int R, int C) {
  __shared__ float tile[32][33];
  const int bx = blockIdx.x * 32;
  const int by = blockIdx.y * 32;
  const int tx = threadIdx.x, ty = threadIdx.y;
  for (int i = ty; i < 32; i += 8) {
    int r = by + i, c = bx + tx;
    if (r < R && c < C) tile[i][tx] = src[(size_t)r * C + c];
  }
  __syncthreads();
  for (int i = ty; i < 32; i += 8) {
    int c = bx + i, r = by + tx;
    if (c < C && r < R) dst[(size_t)c * R + r] = tile[tx][i];
  }
}

__global__ __launch_bounds__(1024) void ntm_generic(Params p) {
  __shared__ float mem[NN][MLD];
  __shared__ __attribute__((aligned(16))) float h_s[HCC];
  __shared__ float c_s[HCC];
  __shared__ __attribute__((aligned(16))) float z_s[ZD];
  __shared__ float gates_s[G4];
  __shared__ float rv_s[HH * MM];
  __shared__ float rw_s[HH][NN];
  __shared__ float ww_s[HH][NN];
  __shared__ float rk_s[HH][MM];
  __shared__ float wk_s[HH][MM];
  __shared__ float ev_s[HH][MM];
  __shared__ float av_s[HH][MM];
  __shared__ float scal_s[6][HH];
  __shared__ float shift_s[2][HH][3];
  __shared__ float memnorm[NN];
  __shared__ float wavescr[8][NN];
  __shared__ float part_s[6][OUTD];

  const int b = blockIdx.x;
  const int tid = threadIdx.x;

  for (int i = tid; i < NN * MM; i += 1024) mem[i >> 6][i & 63] = p.mem0[i];
  if (tid < HCC) { h_s[tid] = 0.0f; c_s[tid] = 0.0f; }
  if (tid < HH * NN) { rw_s[tid >> 7][tid & 127] = 0.0f; ww_s[tid >> 7][tid & 127] = 0.0f; }
  if (tid < HH * MM) rv_s[tid] = 0.0f;
  __syncthreads();

  for (int t = 0; t < SS; ++t) {
    if (tid < NN) {
      float s = 0.0f;
      #pragma unroll 8
      for (int m = 0; m < MM; ++m) { float v = mem[tid][m]; s += v * v; }
      memnorm[tid] = fmaxf(sqrtf(s), 1e-12f);
    } else if (tid < NN + ZD) {
      int k = tid - NN;
      if (k < IND) {
        int xbt = p.x[b * SS + t];
        z_s[k] = p.emb[(size_t)xbt * IND + k];
      } else {
        z_s[k] = rv_s[k - IND];
      }
    }
    __syncthreads();

    {
      const int i = tid;
      float acc = p.b_ih[i] + p.b_hh[i];
      {
        const float* wp = p.wih + (size_t)i * p.wih_sI;
        const int sK = p.wih_sK;
        #pragma unroll 4
        for (int j = 0; j < ZD / 4; ++j) {
          const float* w4 = wp + (size_t)(4 * j) * sK;
          acc += w4[0] * z_s[4 * j] + w4[sK] * z_s[4 * j + 1]
               + w4[2 * sK] * z_s[4 * j + 2] + w4[3 * sK] * z_s[4 * j + 3];
        }
      }
      {
        const float* wp = p.whh + (size_t)i * p.whh_sI;
        const int sK = p.whh_sK;
        #pragma unroll 4
        for (int j = 0; j < HCC / 4; ++j) {
          const float* w4 = wp + (size_t)(4 * j) * sK;
          acc += w4[0] * h_s[4 * j] + w4[sK] * h_s[4 * j + 1]
               + w4[2 * sK] * h_s[4 * j + 2] + w4[3 * sK] * h_s[4 * j + 3];
        }
      }
      gates_s[i] = acc;
    }
    __syncthreads();

    if (tid < HCC) {
      float gi = gates_s[tid], gf = gates_s[HCC + tid];
      float gg = gates_s[2 * HCC + tid], go = gates_s[3 * HCC + tid];
      float cn = sigm(gf) * c_s[tid] + sigm(gi) * tanhf(gg);
      c_s[tid] = cn;
      h_s[tid] = sigm(go) * tanhf(cn);
    }
    __syncthreads();

    {
      const int a = tid >> 8, idx = tid & 255, hh = idx >> 6, m = idx & 63;
      const float* W; const float* bb;
      if (a == 0)      { W = p.rk_W; bb = p.rk_b; }
      else if (a == 1) { W = p.wk_W; bb = p.wk_b; }
      else if (a == 2) { W = p.er_W; bb = p.er_b; }
      else             { W = p.ad_W; bb = p.ad_b; }
      const float* Wp = W + (size_t)(hh * HCC) * MM + m;
      float acc = bb[hh * MM + m];
      #pragma unroll 4
      for (int j = 0; j < HCC / 4; ++j) {
        const float* w4 = Wp + (size_t)(4 * j) * MM;
        acc += w4[0] * h_s[4 * j] + w4[MM] * h_s[4 * j + 1]
             + w4[2 * MM] * h_s[4 * j + 2] + w4[3 * MM] * h_s[4 * j + 3];
      }
      if (a == 0)      rk_s[hh][m] = acc;
      else if (a == 1) wk_s[hh][m] = acc;
      else if (a == 2) ev_s[hh][m] = sigm(acc);
      else             av_s[hh][m] = tanhf(acc);

      if (tid < 48) {
        if (tid < 24) {
          int pp = tid >> 2, h2 = tid & 3;
          const float* W2; const float* b2;
          switch (pp) {
            case 0:  W2 = p.rb_W;  b2 = p.rb_b;  break;
            case 1:  W2 = p.rg_W;  b2 = p.rg_b;  break;
            case 2:  W2 = p.rgm_W; b2 = p.rgm_b; break;
            case 3:  W2 = p.wb_W;  b2 = p.wb_b;  break;
            case 4:  W2 = p.wg_W;  b2 = p.wg_b;  break;
            default: W2 = p.wgm_W; b2 = p.wgm_b; break;
          }
          float acc2 = b2[h2];
          const float* w2 = W2 + (size_t)h2 * HCC;
          #pragma unroll 4
          for (int c = 0; c < HCC; ++c) acc2 += h_s[c] * w2[c];
          float r;
          if (pp == 1 || pp == 4) r = sigm(acc2);
          else { r = softplus_f(acc2); if (pp == 2 || pp == 5) r += 1.0f; }
          scal_s[pp][h2] = r;
        } else {
          int q = tid - 24, pre = q / 12, rr = q % 12, h2 = rr / 3, j = rr % 3;
          const float* W2 = pre ? p.ws_W : p.rs_W;
          const float* b2 = pre ? p.ws_b : p.rs_b;
          float acc2 = b2[h2 * 3 + j];
          const float* w2 = W2 + (size_t)(h2 * HCC) * 3 + j;
          #pragma unroll 4
          for (int c = 0; c < HCC; ++c) acc2 += h_s[c] * w2[(size_t)c * 3];
          shift_s[pre][h2][j] = acc2;
        }
      }
    }
    __syncthreads();

    {
      const int w = tid >> 6, l = tid & 63;
      if (w < 8) {
        const int isW = w >> 2, hh = w & 3;
        const float* kv = isW ? wk_s[hh] : rk_s[hh];
        float* prevw = isW ? ww_s[hh] : rw_s[hh];
        const float beta  = scal_s[isW ? 3 : 0][hh];
        const float g     = scal_s[isW ? 4 : 1][hh];
        const float gamma = scal_s[isW ? 5 : 2][hh];
        float kl = kv[l];
        float kn2 = kl * kl;
        #pragma unroll
        for (int d = 1; d < 64; d <<= 1) kn2 += __shfl_xor(kn2, d, 64);
        const float kn = fmaxf(sqrtf(kn2), 1e-12f);
        float s0 = 0.0f, s1 = 0.0f;
        #pragma unroll 4
        for (int m = 0; m < MM; ++m) {
          float km = kv[m];
          s0 += mem[l][m] * km;
          s1 += mem[l + 64][m] * km;
        }
        float v0 = beta * (s0 / (memnorm[l] * kn));
        float v1 = beta * (s1 / (memnorm[l + 64] * kn));
        float mx = fmaxf(v0, v1);
        #pragma unroll
        for (int d = 1; d < 64; d <<= 1) mx = fmaxf(mx, __shfl_xor(mx, d, 64));
        float e0 = expf(v0 - mx), e1 = expf(v1 - mx);
        float sm = e0 + e1;
        #pragma unroll
        for (int d = 1; d < 64; d <<= 1) sm += __shfl_xor(sm, d, 64);
        const float inv = 1.0f / sm;
        float wg0 = g * (e0 * inv) + (1.0f - g) * prevw[l];
        float wg1 = g * (e1 * inv) + (1.0f - g) * prevw[l + 64];
        wavescr[w][l] = wg0;
        wavescr[w][l + 64] = wg1;
        float sh0 = shift_s[isW][hh][0], sh1 = shift_s[isW][hh][1], sh2 = shift_s[isW][hh][2];
        float shm = fmaxf(sh0, fmaxf(sh1, sh2));
        float es0 = expf(sh0 - shm), es1 = expf(sh1 - shm), es2 = expf(sh2 - shm);
        float esum = es0 + es1 + es2;
        es0 /= esum; es1 /= esum; es2 /= esum;
        float w_0 = es0 * wavescr[w][(l + 1) & 127] + es1 * wavescr[w][l]
                  + es2 * wavescr[w][(l + 127) & 127];
        const int n1 = l + 64;
        float w_1 = es0 * wavescr[w][(n1 + 1) & 127] + es1 * wavescr[w][n1]
                  + es2 * wavescr[w][(n1 + 127) & 127];
        float p0 = powf(w_0, gamma), p1 = powf(w_1, gamma);
        float tot = p0 + p1;
        #pragma unroll
        for (int d = 1; d < 64; d <<= 1) tot += __shfl_xor(tot, d, 64);
        const float invt = 1.0f / tot;
        prevw[l] = p0 * invt;
        prevw[l + 64] = p1 * invt;
      } else {
        const int o = tid & 255, hf = (tid - 512) >> 8;
        const float* Wp = p.outW + (size_t)o * p.outW_sO + (size_t)(hf * 128) * p.outW_sK;
        const int sK = p.outW_sK;
        float acc = 0.0f;
        const float* hp = h_s + hf * 128;
        #pragma unroll 4
        for (int k = 0; k < 128; ++k) acc += hp[k] * Wp[(size_t)k * sK];
        part_s[hf][o] = acc;
      }
    }
    __syncthreads();

    if (tid < HH * MM) {
      const int hh = tid >> 6, m = tid & 63;
      float acc = 0.0f;
      #pragma unroll 4
      for (int n = 0; n < NN; ++n) acc += rw_s[hh][n] * mem[n][m];
      rv_s[tid] = acc;
    }
    __syncthreads();

    {
      const int n = tid >> 3, j = tid & 7, m0 = j * 8;
      const float w0 = ww_s[0][n], w1 = ww_s[1][n], w2 = ww_s[2][n], w3 = ww_s[3][n];
      #pragma unroll
      for (int m = m0; m < m0 + 8; ++m) {
        float e  = w0 * ev_s[0][m] + w1 * ev_s[1][m] + w2 * ev_s[2][m] + w3 * ev_s[3][m];
        float aa = w0 * av_s[0][m] + w1 * av_s[1][m] + w2 * av_s[2][m] + w3 * av_s[3][m];
        mem[n][m] = mem[n][m] * (1.0f - e) + aa;
      }
      const int o = tid & 255, hf = tid >> 8;
      const float* Wp = p.outW + (size_t)o * p.outW_sO + (size_t)(HCC + hf * 64) * p.outW_sK;
      const int sK = p.outW_sK;
      float acc = 0.0f;
      const float* rvp = rv_s + hf * 64;
      #pragma unroll 4
      for (int k = 0; k < 64; ++k) acc += rvp[k] * Wp[(size_t)k * sK];
      part_s[2 + hf][o] = acc;
    }
    __syncthreads();

    if (tid < OUTD) {
      float r = part_s[0][tid] + part_s[1][tid] + part_s[2][tid]
              + part_s[3][tid] + part_s[4][tid] + part_s[5][tid] + p.out_b[tid];
      p.out[((size_t)b * SS + t) * OUTD + tid] = r;
    }
    __syncthreads();
  }
}

extern "C" void kernel_launch(void* const* d_in, const int* in_sizes, int n_in,
                              void* d_out, int out_size, void* d_ws, size_t ws_size,
                              hipStream_t stream) {
  const int*   x     = (const int*)d_in[0];
  const float* emb   = (const float*)d_in[1];
  const float* mem0  = (const float*)d_in[2];
  const float* w_ih  = (const float*)d_in[3];
  const float* w_hh  = (const float*)d_in[4];
  const float* b_ih  = (const float*)d_in[5];
  const float* b_hh  = (const float*)d_in[6];
  const float* rk_W  = (const float*)d_in[7];
  const float* rk_b  = (const float*)d_in[8];
  const float* rb_W  = (const float*)d_in[9];
  const float* rb_b  = (const float*)d_in[10];
  const float* rg_W  = (const float*)d_in[11];
  const float* rg_b  = (const float*)d_in[12];
  const float* rs_W  = (const float*)d_in[13];
  const float* rs_b  = (const float*)d_in[14];
  const float* rgm_W = (const float*)d_in[15];
  const float* rgm_b = (const float*)d_in[16];
  const float* wk_W  = (const float*)d_in[17];
  const float* wk_b  = (const float*)d_in[18];
  const float* wb_W  = (const float*)d_in[19];
  const float* wb_b  = (const float*)d_in[20];
  const float* wg_W  = (const float*)d_in[21];
  const float* wg_b  = (const float*)d_in[22];
  const float* ws_W  = (const float*)d_in[23];
  const float* ws_b  = (const float*)d_in[24];
  const float* wgm_W = (const float*)d_in[25];
  const float* wgm_b = (const float*)d_in[26];
  const float* er_W  = (const float*)d_in[27];
  const float* er_b  = (const float*)d_in[28];
  const float* ad_W  = (const float*)d_in[29];
  const float* ad_b  = (const float*)d_in[30];
  const float* out_W = (const float*)d_in[31];
  const float* out_b = (const float*)d_in[32];
  float* out = (float*)d_out;

  const size_t needCoop = (size_t)NCOOP * sizeof(float);

  if (ws_size >= needCoop) {
    float* ws = (float*)d_ws;
    float* Wg = ws;
    float* Wh = Wg + NWG;
    float* Wo = Wh + NWH;
    float* hb = Wo + NWO;
    float* hv = hb + NHB;
    float* sg = hv + NHV;
    float* sh = sg + NSC;
    unsigned* bar = (unsigned*)(sh + NSH);
    prep_g<<<dim3((NWG + 255) / 256), dim3(256), 0, stream>>>(w_ih, w_hh, Wg);
    prep_h<<<dim3((NWH + 255) / 256), dim3(256), 0, stream>>>(rk_W, wk_W, er_W, ad_W, Wh);
    prep_o<<<dim3((NWO + 255) / 256), dim3(256), 0, stream>>>(out_W, Wo);
    zero_bar<<<dim3((NBAR + 255) / 256), dim3(256), 0, stream>>>(bar);

    CoopP cp{};
    cp.x = x; cp.emb = emb; cp.mem0 = mem0;
    cp.Wg = Wg; cp.Wh = Wh; cp.Wo = Wo;
    cp.hbuf = hb; cp.headv = hv; cp.scalg = sg; cp.shiftg = sh;
    cp.bar = bar;
    cp.b_ih = b_ih; cp.b_hh = b_hh;
    cp.rk_b = rk_b; cp.wk_b = wk_b; cp.er_b = er_b; cp.ad_b = ad_b;
    cp.rb_W = rb_W; cp.rb_b = rb_b; cp.rg_W = rg_W; cp.rg_b = rg_b;
    cp.rgm_W = rgm_W; cp.rgm_b = rgm_b; cp.wb_W = wb_W; cp.wb_b = wb_b;
    cp.wg_W = wg_W; cp.wg_b = wg_b; cp.wgm_W = wgm_W; cp.wgm_b = wgm_b;
    cp.rs_W = rs_W; cp.rs_b = rs_b; cp.ws_W = ws_W; cp.ws_b = ws_b;
    cp.out_b = out_b; cp.out = out;

    ntm_coop<<<dim3(BB * 8), dim3(512), 0, stream>>>(cp);
  } else {
    Params p{};
    p.x = x; p.emb = emb; p.mem0 = mem0;
    p.b_ih = b_ih; p.b_hh = b_hh;
    p.rk_W = rk_W; p.rk_b = rk_b; p.rb_W = rb_W; p.rb_b = rb_b;
    p.rg_W = rg_W; p.rg_b = rg_b; p.rs_W = rs_W; p.rs_b = rs_b;
    p.rgm_W = rgm_W; p.rgm_b = rgm_b;
    p.wk_W = wk_W; p.wk_b = wk_b; p.wb_W = wb_W; p.wb_b = wb_b;
    p.wg_W = wg_W; p.wg_b = wg_b; p.ws_W = ws_W; p.ws_b = ws_b;
    p.wgm_W = wgm_W; p.wgm_b = wgm_b;
    p.er_W = er_W; p.er_b = er_b; p.ad_W = ad_W; p.ad_b = ad_b;
    p.out_b = out_b; p.out = out;

    const size_t nWih  = (size_t)ZD * G4;
    const size_t nWhh  = (size_t)HCC * G4;
    const size_t nWout = (size_t)512 * OUTD;
    const size_t needT = (nWih + nWhh + nWout) * sizeof(float);
    float* ws = (float*)d_ws;

    if (ws_size >= needT) {
      dim3 blk(32, 8);
      transpose_k<<<dim3(ZD / 32, G4 / 32), blk, 0, stream>>>(w_ih, ws, G4, ZD);
      transpose_k<<<dim3(HCC / 32, G4 / 32), blk, 0, stream>>>(w_hh, ws + nWih, G4, HCC);
      transpose_k<<<dim3(512 / 32, OUTD / 32), blk, 0, stream>>>(out_W, ws + nWih + nWhh, OUTD, 512);
      p.wih = ws;                p.wih_sI = 1;   p.wih_sK = G4;
      p.whh = ws + nWih;         p.whh_sI = 1;   p.whh_sK = G4;
      p.outW = ws + nWih + nWhh; p.outW_sK = OUTD; p.outW_sO = 1;
    } else {
      p.wih = w_ih;  p.wih_sI = ZD;  p.wih_sK = 1;
      p.whh = w_hh;  p.whh_sI = HCC; p.whh_sK = 1;
      p.outW = out_W; p.outW_sK = 1; p.outW_sO = 512;
    }
    ntm_generic<<<dim3(BB), dim3(1024), 0, stream>>>(p);
  }
}

// Round 12
// 5629.543 us; speedup vs baseline: 12.1214x; 1.1983x over previous
//
#include <hip/hip_runtime.h>
#include <cstdint>
#include <cstddef>

#define BB   16
#define SS   256
#define IND  128
#define OUTD 256
#define HCC  256
#define G4   1024   // 4*HC
#define ZD   384    // IND + H*M
#define KTOT 640    // ZD + HCC
#define NN   128
#define MM   64
#define HH   4
#define MLD  65

__device__ __forceinline__ float sigm(float x) { return 1.0f / (1.0f + expf(-x)); }
__device__ __forceinline__ float softplus_f(float x) {
  return fmaxf(x, 0.0f) + log1pf(expf(-fabsf(x)));
}

// agent-scope relaxed atomics: bypass L1/L2 to the coherence point (L3).
// Ordering data-vs-counter is provided by the RELEASE RMW in the barrier
// (emits writeback/queue-drain, NOT invalidate -> L2 weights stay warm).
__device__ __forceinline__ void ag_store(float* p_, float v) {
  __hip_atomic_store(p_, v, __ATOMIC_RELAXED, __HIP_MEMORY_SCOPE_AGENT);
}
__device__ __forceinline__ float ag_load(const float* p_) {
  return __hip_atomic_load(p_, __ATOMIC_RELAXED, __HIP_MEMORY_SCOPE_AGENT);
}

// ====================== cooperative-style path (release-barrier) ======================
// ws float layout:
//  Wg4 [8][160][128][4]   655360   gates slice-major float4 layout
//  Wh4 [8][64][128][4]    262144   vec-head slices
//  Wo4 [8][128][32][4]    131072   out slices (full 512 depth)
//  hbuf[2][16][256]         8192
//  headv[16][1024]         16384
//  scalg[16][24]             384
//  shiftg[16][24]            384
//  bar  [16*32 uints]        512   per-batch barrier counters (128B apart)
#define NWG 655360
#define NWH 262144
#define NWO 131072
#define NHB 8192
#define NHV 16384
#define NSC 384
#define NSH 384
#define NBAR 512
#define NCOOP (NWG + NWH + NWO + NHB + NHV + NSC + NSH + NBAR)

__global__ __launch_bounds__(256) void prep_g(const float* __restrict__ wih,
                                              const float* __restrict__ whh,
                                              float* __restrict__ dst) {
  int idx = blockIdx.x * 256 + threadIdx.x;
  if (idx >= NWG) return;
  int j  = idx & 3;
  int li = (idx >> 2) & 127;
  int r  = idx >> 9;              // s*160 + k4
  int k4 = r % 160, s = r / 160;
  int g  = li >> 5, jj = li & 31;
  int i  = g * 256 + s * 32 + jj;
  int k  = k4 * 4 + j;
  dst[idx] = (k < ZD) ? wih[(size_t)i * ZD + k] : whh[(size_t)i * HCC + (k - ZD)];
}

__global__ __launch_bounds__(256) void prep_h(const float* __restrict__ rkW,
                                              const float* __restrict__ wkW,
                                              const float* __restrict__ erW,
                                              const float* __restrict__ adW,
                                              float* __restrict__ dst) {
  int idx = blockIdx.x * 256 + threadIdx.x;
  if (idx >= NWH) return;
  int j  = idx & 3;
  int li = (idx >> 2) & 127;
  int r  = idx >> 9;              // s*64 + c4
  int c4 = r & 63, s = r >> 6;
  int oh = s * 128 + li;
  int a = oh >> 8, hh = (oh >> 6) & 3, m = oh & 63;
  int c = c4 * 4 + j;
  const float* W = (a == 0) ? rkW : (a == 1) ? wkW : (a == 2) ? erW : adW;
  dst[idx] = W[((size_t)hh * HCC + c) * MM + m];
}

__global__ __launch_bounds__(256) void prep_o(const float* __restrict__ outW,
                                              float* __restrict__ dst) {
  int idx = blockIdx.x * 256 + threadIdx.x;
  if (idx >= NWO) return;
  int j  = idx & 3;
  int lo = (idx >> 2) & 31;
  int r  = idx >> 7;              // s*128 + k4
  int k4 = r & 127, s = r >> 7;
  int o = s * 32 + lo;
  int k = k4 * 4 + j;
  dst[idx] = outW[(size_t)o * 512 + k];
}

__global__ __launch_bounds__(256) void zero_bar(unsigned* __restrict__ bar) {
  int idx = blockIdx.x * 256 + threadIdx.x;
  if (idx < NBAR) bar[idx] = 0u;
}

struct CoopP {
  const int* x; const float* emb; const float* mem0;
  const float* Wg; const float* Wh; const float* Wo;
  float* hbuf; float* headv; float* scalg; float* shiftg;
  unsigned* bar;
  const float* b_ih; const float* b_hh;
  const float* rk_b; const float* wk_b; const float* er_b; const float* ad_b;
  const float* rb_W; const float* rb_b; const float* rg_W; const float* rg_b;
  const float* rgm_W; const float* rgm_b; const float* wb_W; const float* wb_b;
  const float* wg_W; const float* wg_b; const float* wgm_W; const float* wgm_b;
  const float* rs_W; const float* rs_b; const float* ws_W; const float* ws_b;
  const float* out_b; float* out;
};

// 128 blocks = 16 batches x 8 slices, 512 threads. Release-ordered per-batch barriers.
__global__ __launch_bounds__(512) void ntm_coop(CoopP p) {
  __shared__ float mem[NN][MLD];
  __shared__ __attribute__((aligned(16))) float zh_s[KTOT];
  __shared__ __attribute__((aligned(16))) float h_loc[HCC];
  __shared__ __attribute__((aligned(16))) float rv_loc[HH * MM];
  __shared__ float gpart[128][5];
  __shared__ float hpart[128][5];
  __shared__ float opart[32][17];
  __shared__ float rk_s[HH][MM], wk_s[HH][MM], ev_s[HH][MM], av_s[HH][MM];
  __shared__ float rw_s[HH][NN], ww_s[HH][NN];
  __shared__ float memnorm[NN];
  __shared__ float wavescr[8][NN];
  __shared__ float scal_s[6][HH];
  __shared__ float shiftr[2][HH][3];
  __shared__ float c_loc[32];

  const int tid  = threadIdx.x;
  const int bid  = blockIdx.x;
  const int s    = bid & 7;
  const int b    = bid >> 3;
  const int lane = tid & 63;
  const int wv   = tid >> 6;

  unsigned* __restrict__ mybar = p.bar + b * 32;
  unsigned bar_target = 0;

  // hoisted per-thread constants
  float biasg[4];
  if (tid < 32) {
    #pragma unroll
    for (int g = 0; g < 4; ++g) {
      int i = g * 256 + s * 32 + tid;
      biasg[g] = p.b_ih[i] + p.b_hh[i];
    }
  }
  float bias_vh = 0.0f;
  if (tid < 128) {
    int oh = s * 128 + tid;
    int a = oh >> 8, hh = (oh >> 6) & 3, m = oh & 63;
    const float* bb = (a == 0) ? p.rk_b : (a == 1) ? p.wk_b : (a == 2) ? p.er_b : p.ad_b;
    bias_vh = bb[hh * MM + m];
  }
  const float outb = (tid < 32) ? p.out_b[s * 32 + tid] : 0.0f;

  // init
  for (int i = tid; i < NN * MM; i += 512) mem[i >> 6][i & 63] = p.mem0[i];
  if (tid < 32) c_loc[tid] = 0.0f;
  if (tid < HH * MM) rv_loc[tid] = 0.0f;
  { rw_s[tid >> 7][tid & 127] = 0.0f; ww_s[tid >> 7][tid & 127] = 0.0f; }
  if (tid < 32) ag_store(&p.hbuf[(size_t)b * 256 + s * 32 + tid], 0.0f);   // hbuf[0]

  // ---- per-batch barrier (8 blocks, monotonic counter) ----
  // Arrival is a RELEASE RMW at agent scope: LLVM emits the store-queue
  // drain/L2-writeback (buffer_wbl2, no invalidate) before the atomic, so
  // all prior ag_stores are globally visible before the counter bump, and
  // clean L2 lines (the weight slices) stay resident. The spin stays
  // RELAXED; data reads are L2-bypassing atomics, so no acquire/invalidate
  // is needed on the consumer side.
  #define BATCH_BARRIER()                                                        \
    do {                                                                         \
      bar_target += 8;                                                           \
      __syncthreads();                                                           \
      if (tid == 0) {                                                            \
        __hip_atomic_fetch_add(mybar, 1u, __ATOMIC_RELEASE,                      \
                               __HIP_MEMORY_SCOPE_AGENT);                        \
        while (__hip_atomic_load(mybar, __ATOMIC_RELAXED,                        \
                                 __HIP_MEMORY_SCOPE_AGENT) < bar_target) {       \
          __builtin_amdgcn_s_sleep(2);                                           \
        }                                                                        \
      }                                                                          \
      __syncthreads();                                                           \
    } while (0)

  BATCH_BARRIER();   // hbuf[0] visible to all 8 blocks of this batch

  const int* __restrict__ xrow = p.x + b * SS;
  const float4* __restrict__ Wg4 = (const float4*)p.Wg + (size_t)s * 160 * 128;
  const float4* __restrict__ Wh4 = (const float4*)p.Wh + (size_t)s * 64 * 128;
  const float4* __restrict__ Wo4 = (const float4*)p.Wo + (size_t)s * 128 * 32;

  for (int t = 0; t < SS; ++t) {
    const int pr = t & 1, cu = pr ^ 1;

    // ---- phase 1a: build zh = [emb, rv, h_prev] ----
    {
      float* hprev = p.hbuf + (size_t)pr * 16 * 256 + b * 256;
      const int xbt = xrow[t];
      for (int k = tid; k < KTOT; k += 512) {
        float v;
        if (k < IND)      v = p.emb[(size_t)xbt * IND + k];
        else if (k < ZD)  v = rv_loc[k - IND];
        else              v = ag_load(&hprev[k - ZD]);
        zh_s[k] = v;
      }
    }
    __syncthreads();

    // ---- phase 1b: gates slice partials (128 rows x 4-way split-K) ----
    {
      const int li = tid & 127, q = tid >> 7;   // q in [0,4)
      const float4* zh4 = (const float4*)zh_s;
      const int k40 = q * 40;
      float acc = 0.0f;
      #pragma unroll 8
      for (int kk = 0; kk < 40; ++kk) {
        float4 w = Wg4[(size_t)(k40 + kk) * 128 + li];
        float4 z = zh4[k40 + kk];
        acc += w.x * z.x + w.y * z.y + w.z * z.z + w.w * z.w;
      }
      gpart[li][q] = acc;
    }
    __syncthreads();

    // ---- phase 1c: reduce + LSTM + write h slice ----
    if (tid < 32) {
      float gv[4];
      #pragma unroll
      for (int g = 0; g < 4; ++g) {
        int li = g * 32 + tid;
        gv[g] = gpart[li][0] + gpart[li][1] + gpart[li][2] + gpart[li][3] + biasg[g];
      }
      float cn = sigm(gv[1]) * c_loc[tid] + sigm(gv[0]) * tanhf(gv[2]);
      c_loc[tid] = cn;
      float hv = sigm(gv[3]) * tanhf(cn);
      ag_store(&p.hbuf[(size_t)cu * 16 * 256 + b * 256 + s * 32 + tid], hv);
    }
    BATCH_BARRIER();   // SYNC A: full h ready

    // ---- phase 2: copy full h local ----
    if (tid < HCC) h_loc[tid] = ag_load(&p.hbuf[(size_t)cu * 16 * 256 + b * 256 + tid]);
    __syncthreads();

    // vec-head slice partials (128 outs x 4-way split-K over 256)
    {
      const int li = tid & 127, q = tid >> 7;
      const float4* h4 = (const float4*)h_loc;
      const int c40 = q * 16;
      float acc = 0.0f;
      #pragma unroll 8
      for (int cc = 0; cc < 16; ++cc) {
        float4 w = Wh4[(size_t)(c40 + cc) * 128 + li];
        float4 h = h4[c40 + cc];
        acc += w.x * h.x + w.y * h.y + w.z * h.z + w.w * h.w;
      }
      hpart[li][q] = acc;
    }
    // out h-part partials (32 outs x 16-way split-K over 256)
    {
      const int lo = tid & 31, q = tid >> 5;    // q in [0,16)
      const float4* h4 = (const float4*)h_loc;
      float acc = 0.0f;
      #pragma unroll
      for (int kk = 0; kk < 4; ++kk) {
        int k4 = q * 4 + kk;
        float4 w = Wo4[(size_t)k4 * 32 + lo];
        float4 h = h4[k4];
        acc += w.x * h.x + w.y * h.y + w.z * h.z + w.w * h.w;
      }
      opart[lo][q] = acc;
    }
    // 6 scalar/shift dots for this slice (waves 0..5)
    if (wv < 6) {
      const int d = s * 6 + wv;
      float partial = 0.0f;
      if (d < 24) {
        const int pp = d >> 2, h2 = d & 3;
        const float* W2 = (pp == 0) ? p.rb_W : (pp == 1) ? p.rg_W : (pp == 2) ? p.rgm_W
                        : (pp == 3) ? p.wb_W : (pp == 4) ? p.wg_W : p.wgm_W;
        #pragma unroll
        for (int qq = 0; qq < 4; ++qq)
          partial += h_loc[qq * 64 + lane] * W2[h2 * HCC + qq * 64 + lane];
        #pragma unroll
        for (int dd = 1; dd < 64; dd <<= 1) partial += __shfl_xor(partial, dd, 64);
        if (lane == 0) {
          const float* b2 = (pp == 0) ? p.rb_b : (pp == 1) ? p.rg_b : (pp == 2) ? p.rgm_b
                          : (pp == 3) ? p.wb_b : (pp == 4) ? p.wg_b : p.wgm_b;
          float a2 = partial + b2[h2];
          float r;
          if (pp == 1 || pp == 4) r = sigm(a2);
          else { r = softplus_f(a2); if (pp == 2 || pp == 5) r += 1.0f; }
          ag_store(&p.scalg[b * 24 + pp * 4 + h2], r);
        }
      } else {
        const int q2 = d - 24, pre = q2 / 12, rr = q2 % 12, h2 = rr / 3, jj = rr % 3;
        const float* W2 = pre ? p.ws_W : p.rs_W;
        #pragma unroll
        for (int qq = 0; qq < 4; ++qq)
          partial += h_loc[qq * 64 + lane] * W2[(size_t)(h2 * HCC + qq * 64 + lane) * 3 + jj];
        #pragma unroll
        for (int dd = 1; dd < 64; dd <<= 1) partial += __shfl_xor(partial, dd, 64);
        if (lane == 0) {
          const float* b2 = pre ? p.ws_b : p.rs_b;
          ag_store(&p.shiftg[b * 24 + pre * 12 + h2 * 3 + jj], partial + b2[h2 * 3 + jj]);
        }
      }
    }
    __syncthreads();
    // vec-head finalize -> headv
    if (tid < 128) {
      int oh = s * 128 + tid;
      int a = oh >> 8;
      float acc = hpart[tid][0] + hpart[tid][1] + hpart[tid][2] + hpart[tid][3] + bias_vh;
      float v = (a == 2) ? sigm(acc) : (a == 3) ? tanhf(acc) : acc;
      ag_store(&p.headv[b * 1024 + oh], v);
    }
    BATCH_BARRIER();   // SYNC B: all head outputs ready

    // ---- phase 3: replicated addressing + rv + mem update + out finalize ----
    for (int oh = tid; oh < 1024; oh += 512) {
      float v = ag_load(&p.headv[b * 1024 + oh]);
      int a = oh >> 8, hh2 = (oh >> 6) & 3, m = oh & 63;
      if (a == 0)      rk_s[hh2][m] = v;
      else if (a == 1) wk_s[hh2][m] = v;
      else if (a == 2) ev_s[hh2][m] = v;
      else             av_s[hh2][m] = v;
    }
    if (tid < 24) ((float*)scal_s)[tid] = ag_load(&p.scalg[b * 24 + tid]);
    else if (tid < 48) ((float*)shiftr)[tid - 24] = ag_load(&p.shiftg[b * 24 + tid - 24]);
    if (tid < NN) {
      float ss = 0.0f;
      #pragma unroll 8
      for (int m = 0; m < MM; ++m) { float v = mem[tid][m]; ss += v * v; }
      memnorm[tid] = fmaxf(sqrtf(ss), 1e-12f);
    }
    __syncthreads();

    // addressing: 8 waves = {read,write} x 4 heads
    {
      const int isW = wv >> 2, hh = wv & 3;
      const int l = lane;
      const float* kv = isW ? wk_s[hh] : rk_s[hh];
      float* prevw = isW ? ww_s[hh] : rw_s[hh];
      const float beta  = scal_s[isW ? 3 : 0][hh];
      const float g     = scal_s[isW ? 4 : 1][hh];
      const float gamma = scal_s[isW ? 5 : 2][hh];
      float kl = kv[l];
      float kn2 = kl * kl;
      #pragma unroll
      for (int d = 1; d < 64; d <<= 1) kn2 += __shfl_xor(kn2, d, 64);
      const float kn = fmaxf(sqrtf(kn2), 1e-12f);
      float s0 = 0.0f, s1 = 0.0f;
      #pragma unroll 4
      for (int m = 0; m < MM; ++m) {
        float km = kv[m];
        s0 += mem[l][m] * km;
        s1 += mem[l + 64][m] * km;
      }
      float v0 = beta * (s0 / (memnorm[l] * kn));
      float v1 = beta * (s1 / (memnorm[l + 64] * kn));
      float mx = fmaxf(v0, v1);
      #pragma unroll
      for (int d = 1; d < 64; d <<= 1) mx = fmaxf(mx, __shfl_xor(mx, d, 64));
      float e0 = expf(v0 - mx), e1 = expf(v1 - mx);
      float sm = e0 + e1;
      #pragma unroll
      for (int d = 1; d < 64; d <<= 1) sm += __shfl_xor(sm, d, 64);
      const float inv = 1.0f / sm;
      float wg0 = g * (e0 * inv) + (1.0f - g) * prevw[l];
      float wg1 = g * (e1 * inv) + (1.0f - g) * prevw[l + 64];
      wavescr[wv][l] = wg0;
      wavescr[wv][l + 64] = wg1;
      float sh0 = shiftr[isW][hh][0], sh1 = shiftr[isW][hh][1], sh2 = shiftr[isW][hh][2];
      float shm = fmaxf(sh0, fmaxf(sh1, sh2));
      float es0 = expf(sh0 - shm), es1 = expf(sh1 - shm), es2 = expf(sh2 - shm);
      float esum = es0 + es1 + es2;
      es0 /= esum; es1 /= esum; es2 /= esum;
      float w_0 = es0 * wavescr[wv][(l + 1) & 127] + es1 * wavescr[wv][l]
                + es2 * wavescr[wv][(l + 127) & 127];
      const int n1 = l + 64;
      float w_1 = es0 * wavescr[wv][(n1 + 1) & 127] + es1 * wavescr[wv][n1]
                + es2 * wavescr[wv][(n1 + 127) & 127];
      float p0 = powf(w_0, gamma), p1 = powf(w_1, gamma);
      float tot = p0 + p1;
      #pragma unroll
      for (int d = 1; d < 64; d <<= 1) tot += __shfl_xor(tot, d, 64);
      const float invt = 1.0f / tot;
      prevw[l] = p0 * invt;
      prevw[l + 64] = p1 * invt;
    }
    __syncthreads();

    // rv = rw . mem (OLD mem)
    if (tid < HH * MM) {
      const int hh2 = tid >> 6, m = tid & 63;
      float acc = 0.0f;
      #pragma unroll 4
      for (int n = 0; n < NN; ++n) acc += rw_s[hh2][n] * mem[n][m];
      rv_loc[tid] = acc;
    }
    __syncthreads();

    // mem erase+add (replicated) + out rv-part partials
    {
      const int n = tid >> 2, m0 = (tid & 3) * 16;
      const float w0 = ww_s[0][n], w1 = ww_s[1][n], w2 = ww_s[2][n], w3 = ww_s[3][n];
      #pragma unroll
      for (int m = m0; m < m0 + 16; ++m) {
        float e  = w0 * ev_s[0][m] + w1 * ev_s[1][m] + w2 * ev_s[2][m] + w3 * ev_s[3][m];
        float aa = w0 * av_s[0][m] + w1 * av_s[1][m] + w2 * av_s[2][m] + w3 * av_s[3][m];
        mem[n][m] = mem[n][m] * (1.0f - e) + aa;
      }
      const int lo = tid & 31, q = tid >> 5;
      const float4* rv4 = (const float4*)rv_loc;
      float acc = 0.0f;
      #pragma unroll
      for (int kk = 0; kk < 4; ++kk) {
        int k4 = 64 + q * 4 + kk;
        float4 w = Wo4[(size_t)k4 * 32 + lo];
        float4 r = rv4[k4 - 64];
        acc += w.x * r.x + w.y * r.y + w.z * r.z + w.w * r.w;
      }
      opart[lo][q] += acc;
    }
    __syncthreads();

    // final logits for this o-slice
    if (tid < 32) {
      float r = outb;
      #pragma unroll
      for (int q = 0; q < 16; ++q) r += opart[tid][q];
      p.out[((size_t)b * SS + t) * OUTD + s * 32 + tid] = r;
    }
  }
  #undef BATCH_BARRIER
}

// ====================== fallback paths ======================
struct Params {
  const int*   x;
  const float* emb;
  const float* mem0;
  const float* wih; int wih_sI, wih_sK;
  const float* whh; int whh_sI, whh_sK;
  const float* b_ih; const float* b_hh;
  const float* rk_W; const float* rk_b;
  const float* rb_W; const float* rb_b;
  const float* rg_W; const float* rg_b;
  const float* rs_W; const float* rs_b;
  const float* rgm_W; const float* rgm_b;
  const float* wk_W; const float* wk_b;
  const float* wb_W; const float* wb_b;
  const float* wg_W; const float* wg_b;
  const float* ws_W; const float* ws_b;
  const float* wgm_W; const float* wgm_b;
  const float* er_W; const float* er_b;
  const float* ad_W; const float* ad_b;
  const float* outW; int outW_sK, outW_sO;
  const float* out_b;
  float* out;
};

__global__ __launch_bounds__(256) void transpose_k(const float* __restrict__ src,
                                                   float* __restrict__ dst,
                                                   int R, int C) {
  __shared__ float tile[32][33];
  const int bx = blockIdx.x * 32;
  const int by = blockIdx.y * 32;
  const int tx = threadIdx.x, ty = threadIdx.y;
  for (int i = ty; i < 32; i += 8) {
    int r = by + i, c = bx + tx;
    if (r < R && c < C) tile[i][tx] = src[(size_t)r * C + c];
  }
  __syncthreads();
  for (int i = ty; i < 32; i += 8) {
    int c = bx + i, r = by + tx;
    if (c < C && r < R) dst[(size_t)c * R + r] = tile[tx][i];
  }
}

__global__ __launch_bounds__(1024) void ntm_generic(Params p) {
  __shared__ float mem[NN][MLD];
  __shared__ __attribute__((aligned(16))) float h_s[HCC];
  __shared__ float c_s[HCC];
  __shared__ __attribute__((aligned(16))) float z_s[ZD];
  __shared__ float gates_s[G4];
  __shared__ float rv_s[HH * MM];
  __shared__ float rw_s[HH][NN];
  __shared__ float ww_s[HH][NN];
  __shared__ float rk_s[HH][MM];
  __shared__ float wk_s[HH][MM];
  __shared__ float ev_s[HH][MM];
  __shared__ float av_s[HH][MM];
  __shared__ float scal_s[6][HH];
  __shared__ float shift_s[2][HH][3];
  __shared__ float memnorm[NN];
  __shared__ float wavescr[8][NN];
  __shared__ float part_s[6][OUTD];

  const int b = blockIdx.x;
  const int tid = threadIdx.x;

  for (int i = tid; i < NN * MM; i += 1024) mem[i >> 6][i & 63] = p.mem0[i];
  if (tid < HCC) { h_s[tid] = 0.0f; c_s[tid] = 0.0f; }
  if (tid < HH * NN) { rw_s[tid >> 7][tid & 127] = 0.0f; ww_s[tid >> 7][tid & 127] = 0.0f; }
  if (tid < HH * MM) rv_s[tid] = 0.0f;
  __syncthreads();

  for (int t = 0; t < SS; ++t) {
    if (tid < NN) {
      float s = 0.0f;
      #pragma unroll 8
      for (int m = 0; m < MM; ++m) { float v = mem[tid][m]; s += v * v; }
      memnorm[tid] = fmaxf(sqrtf(s), 1e-12f);
    } else if (tid < NN + ZD) {
      int k = tid - NN;
      if (k < IND) {
        int xbt = p.x[b * SS + t];
        z_s[k] = p.emb[(size_t)xbt * IND + k];
      } else {
        z_s[k] = rv_s[k - IND];
      }
    }
    __syncthreads();

    {
      const int i = tid;
      float acc = p.b_ih[i] + p.b_hh[i];
      {
        const float* wp = p.wih + (size_t)i * p.wih_sI;
        const int sK = p.wih_sK;
        #pragma unroll 4
        for (int j = 0; j < ZD / 4; ++j) {
          const float* w4 = wp + (size_t)(4 * j) * sK;
          acc += w4[0] * z_s[4 * j] + w4[sK] * z_s[4 * j + 1]
               + w4[2 * sK] * z_s[4 * j + 2] + w4[3 * sK] * z_s[4 * j + 3];
        }
      }
      {
        const float* wp = p.whh + (size_t)i * p.whh_sI;
        const int sK = p.whh_sK;
        #pragma unroll 4
        for (int j = 0; j < HCC / 4; ++j) {
          const float* w4 = wp + (size_t)(4 * j) * sK;
          acc += w4[0] * h_s[4 * j] + w4[sK] * h_s[4 * j + 1]
               + w4[2 * sK] * h_s[4 * j + 2] + w4[3 * sK] * h_s[4 * j + 3];
        }
      }
      gates_s[i] = acc;
    }
    __syncthreads();

    if (tid < HCC) {
      float gi = gates_s[tid], gf = gates_s[HCC + tid];
      float gg = gates_s[2 * HCC + tid], go = gates_s[3 * HCC + tid];
      float cn = sigm(gf) * c_s[tid] + sigm(gi) * tanhf(gg);
      c_s[tid] = cn;
      h_s[tid] = sigm(go) * tanhf(cn);
    }
    __syncthreads();

    {
      const int a = tid >> 8, idx = tid & 255, hh = idx >> 6, m = idx & 63;
      const float* W; const float* bb;
      if (a == 0)      { W = p.rk_W; bb = p.rk_b; }
      else if (a == 1) { W = p.wk_W; bb = p.wk_b; }
      else if (a == 2) { W = p.er_W; bb = p.er_b; }
      else             { W = p.ad_W; bb = p.ad_b; }
      const float* Wp = W + (size_t)(hh * HCC) * MM + m;
      float acc = bb[hh * MM + m];
      #pragma unroll 4
      for (int j = 0; j < HCC / 4; ++j) {
        const float* w4 = Wp + (size_t)(4 * j) * MM;
        acc += w4[0] * h_s[4 * j] + w4[MM] * h_s[4 * j + 1]
             + w4[2 * MM] * h_s[4 * j + 2] + w4[3 * MM] * h_s[4 * j + 3];
      }
      if (a == 0)      rk_s[hh][m] = acc;
      else if (a == 1) wk_s[hh][m] = acc;
      else if (a == 2) ev_s[hh][m] = sigm(acc);
      else             av_s[hh][m] = tanhf(acc);

      if (tid < 48) {
        if (tid < 24) {
          int pp = tid >> 2, h2 = tid & 3;
          const float* W2; const float* b2;
          switch (pp) {
            case 0:  W2 = p.rb_W;  b2 = p.rb_b;  break;
            case 1:  W2 = p.rg_W;  b2 = p.rg_b;  break;
            case 2:  W2 = p.rgm_W; b2 = p.rgm_b; break;
            case 3:  W2 = p.wb_W;  b2 = p.wb_b;  break;
            case 4:  W2 = p.wg_W;  b2 = p.wg_b;  break;
            default: W2 = p.wgm_W; b2 = p.wgm_b; break;
          }
          float acc2 = b2[h2];
          const float* w2 = W2 + (size_t)h2 * HCC;
          #pragma unroll 4
          for (int c = 0; c < HCC; ++c) acc2 += h_s[c] * w2[c];
          float r;
          if (pp == 1 || pp == 4) r = sigm(acc2);
          else { r = softplus_f(acc2); if (pp == 2 || pp == 5) r += 1.0f; }
          scal_s[pp][h2] = r;
        } else {
          int q = tid - 24, pre = q / 12, rr = q % 12, h2 = rr / 3, j = rr % 3;
          const float* W2 = pre ? p.ws_W : p.rs_W;
          const float* b2 = pre ? p.ws_b : p.rs_b;
          float acc2 = b2[h2 * 3 + j];
          const float* w2 = W2 + (size_t)(h2 * HCC) * 3 + j;
          #pragma unroll 4
          for (int c = 0; c < HCC; ++c) acc2 += h_s[c] * w2[(size_t)c * 3];
          shift_s[pre][h2][j] = acc2;
        }
      }
    }
    __syncthreads();

    {
      const int w = tid >> 6, l = tid & 63;
      if (w < 8) {
        const int isW = w >> 2, hh = w & 3;
        const float* kv = isW ? wk_s[hh] : rk_s[hh];
        float* prevw = isW ? ww_s[hh] : rw_s[hh];
        const float beta  = scal_s[isW ? 3 : 0][hh];
        const float g     = scal_s[isW ? 4 : 1][hh];
        const float gamma = scal_s[isW ? 5 : 2][hh];
        float kl = kv[l];
        float kn2 = kl * kl;
        #pragma unroll
        for (int d = 1; d < 64; d <<= 1) kn2 += __shfl_xor(kn2, d, 64);
        const float kn = fmaxf(sqrtf(kn2), 1e-12f);
        float s0 = 0.0f, s1 = 0.0f;
        #pragma unroll 4
        for (int m = 0; m < MM; ++m) {
          float km = kv[m];
          s0 += mem[l][m] * km;
          s1 += mem[l + 64][m] * km;
        }
        float v0 = beta * (s0 / (memnorm[l] * kn));
        float v1 = beta * (s1 / (memnorm[l + 64] * kn));
        float mx = fmaxf(v0, v1);
        #pragma unroll
        for (int d = 1; d < 64; d <<= 1) mx = fmaxf(mx, __shfl_xor(mx, d, 64));
        float e0 = expf(v0 - mx), e1 = expf(v1 - mx);
        float sm = e0 + e1;
        #pragma unroll
        for (int d = 1; d < 64; d <<= 1) sm += __shfl_xor(sm, d, 64);
        const float inv = 1.0f / sm;
        float wg0 = g * (e0 * inv) + (1.0f - g) * prevw[l];
        float wg1 = g * (e1 * inv) + (1.0f - g) * prevw[l + 64];
        wavescr[w][l] = wg0;
        wavescr[w][l + 64] = wg1;
        float sh0 = shift_s[isW][hh][0], sh1 = shift_s[isW][hh][1], sh2 = shift_s[isW][hh][2];
        float shm = fmaxf(sh0, fmaxf(sh1, sh2));
        float es0 = expf(sh0 - shm), es1 = expf(sh1 - shm), es2 = expf(sh2 - shm);
        float esum = es0 + es1 + es2;
        es0 /= esum; es1 /= esum; es2 /= esum;
        float w_0 = es0 * wavescr[w][(l + 1) & 127] + es1 * wavescr[w][l]
                  + es2 * wavescr[w][(l + 127) & 127];
        const int n1 = l + 64;
        float w_1 = es0 * wavescr[w][(n1 + 1) & 127] + es1 * wavescr[w][n1]
                  + es2 * wavescr[w][(n1 + 127) & 127];
        float p0 = powf(w_0, gamma), p1 = powf(w_1, gamma);
        float tot = p0 + p1;
        #pragma unroll
        for (int d = 1; d < 64; d <<= 1) tot += __shfl_xor(tot, d, 64);
        const float invt = 1.0f / tot;
        prevw[l] = p0 * invt;
        prevw[l + 64] = p1 * invt;
      } else {
        const int o = tid & 255, hf = (tid - 512) >> 8;
        const float* Wp = p.outW + (size_t)o * p.outW_sO + (size_t)(hf * 128) * p.outW_sK;
        const int sK = p.outW_sK;
        float acc = 0.0f;
        const float* hp = h_s + hf * 128;
        #pragma unroll 4
        for (int k = 0; k < 128; ++k) acc += hp[k] * Wp[(size_t)k * sK];
        part_s[hf][o] = acc;
      }
    }
    __syncthreads();

    if (tid < HH * MM) {
      const int hh = tid >> 6, m = tid & 63;
      float acc = 0.0f;
      #pragma unroll 4
      for (int n = 0; n < NN; ++n) acc += rw_s[hh][n] * mem[n][m];
      rv_s[tid] = acc;
    }
    __syncthreads();

    {
      const int n = tid >> 3, j = tid & 7, m0 = j * 8;
      const float w0 = ww_s[0][n], w1 = ww_s[1][n], w2 = ww_s[2][n], w3 = ww_s[3][n];
      #pragma unroll
      for (int m = m0; m < m0 + 8; ++m) {
        float e  = w0 * ev_s[0][m] + w1 * ev_s[1][m] + w2 * ev_s[2][m] + w3 * ev_s[3][m];
        float aa = w0 * av_s[0][m] + w1 * av_s[1][m] + w2 * av_s[2][m] + w3 * av_s[3][m];
        mem[n][m] = mem[n][m] * (1.0f - e) + aa;
      }
      const int o = tid & 255, hf = tid >> 8;
      const float* Wp = p.outW + (size_t)o * p.outW_sO + (size_t)(HCC + hf * 64) * p.outW_sK;
      const int sK = p.outW_sK;
      float acc = 0.0f;
      const float* rvp = rv_s + hf * 64;
      #pragma unroll 4
      for (int k = 0; k < 64; ++k) acc += rvp[k] * Wp[(size_t)k * sK];
      part_s[2 + hf][o] = acc;
    }
    __syncthreads();

    if (tid < OUTD) {
      float r = part_s[0][tid] + part_s[1][tid] + part_s[2][tid]
              + part_s[3][tid] + part_s[4][tid] + part_s[5][tid] + p.out_b[tid];
      p.out[((size_t)b * SS + t) * OUTD + tid] = r;
    }
    __syncthreads();
  }
}

extern "C" void kernel_launch(void* const* d_in, const int* in_sizes, int n_in,
                              void* d_out, int out_size, void* d_ws, size_t ws_size,
                              hipStream_t stream) {
  const int*   x     = (const int*)d_in[0];
  const float* emb   = (const float*)d_in[1];
  const float* mem0  = (const float*)d_in[2];
  const float* w_ih  = (const float*)d_in[3];
  const float* w_hh  = (const float*)d_in[4];
  const float* b_ih  = (const float*)d_in[5];
  const float* b_hh  = (const float*)d_in[6];
  const float* rk_W  = (const float*)d_in[7];
  const float* rk_b  = (const float*)d_in[8];
  const float* rb_W  = (const float*)d_in[9];
  const float* rb_b  = (const float*)d_in[10];
  const float* rg_W  = (const float*)d_in[11];
  const float* rg_b  = (const float*)d_in[12];
  const float* rs_W  = (const float*)d_in[13];
  const float* rs_b  = (const float*)d_in[14];
  const float* rgm_W = (const float*)d_in[15];
  const float* rgm_b = (const float*)d_in[16];
  const float* wk_W  = (const float*)d_in[17];
  const float* wk_b  = (const float*)d_in[18];
  const float* wb_W  = (const float*)d_in[19];
  const float* wb_b  = (const float*)d_in[20];
  const float* wg_W  = (const float*)d_in[21];
  const float* wg_b  = (const float*)d_in[22];
  const float* ws_W  = (const float*)d_in[23];
  const float* ws_b  = (const float*)d_in[24];
  const float* wgm_W = (const float*)d_in[25];
  const float* wgm_b = (const float*)d_in[26];
  const float* er_W  = (const float*)d_in[27];
  const float* er_b  = (const float*)d_in[28];
  const float* ad_W  = (const float*)d_in[29];
  const float* ad_b  = (const float*)d_in[30];
  const float* out_W = (const float*)d_in[31];
  const float* out_b = (const float*)d_in[32];
  float* out = (float*)d_out;

  const size_t needCoop = (size_t)NCOOP * sizeof(float);

  if (ws_size >= needCoop) {
    float* ws = (float*)d_ws;
    float* Wg = ws;
    float* Wh = Wg + NWG;
    float* Wo = Wh + NWH;
    float* hb = Wo + NWO;
    float* hv = hb + NHB;
    float* sg = hv + NHV;
    float* sh = sg + NSC;
    unsigned* bar = (unsigned*)(sh + NSH);
    prep_g<<<dim3((NWG + 255) / 256), dim3(256), 0, stream>>>(w_ih, w_hh, Wg);
    prep_h<<<dim3((NWH + 255) / 256), dim3(256), 0, stream>>>(rk_W, wk_W, er_W, ad_W, Wh);
    prep_o<<<dim3((NWO + 255) / 256), dim3(256), 0, stream>>>(out_W, Wo);
    zero_bar<<<dim3((NBAR + 255) / 256), dim3(256), 0, stream>>>(bar);

    CoopP cp{};
    cp.x = x; cp.emb = emb; cp.mem0 = mem0;
    cp.Wg = Wg; cp.Wh = Wh; cp.Wo = Wo;
    cp.hbuf = hb; cp.headv = hv; cp.scalg = sg; cp.shiftg = sh;
    cp.bar = bar;
    cp.b_ih = b_ih; cp.b_hh = b_hh;
    cp.rk_b = rk_b; cp.wk_b = wk_b; cp.er_b = er_b; cp.ad_b = ad_b;
    cp.rb_W = rb_W; cp.rb_b = rb_b; cp.rg_W = rg_W; cp.rg_b = rg_b;
    cp.rgm_W = rgm_W; cp.rgm_b = rgm_b; cp.wb_W = wb_W; cp.wb_b = wb_b;
    cp.wg_W = wg_W; cp.wg_b = wg_b; cp.wgm_W = wgm_W; cp.wgm_b = wgm_b;
    cp.rs_W = rs_W; cp.rs_b = rs_b; cp.ws_W = ws_W; cp.ws_b = ws_b;
    cp.out_b = out_b; cp.out = out;

    ntm_coop<<<dim3(BB * 8), dim3(512), 0, stream>>>(cp);
  } else {
    Params p{};
    p.x = x; p.emb = emb; p.mem0 = mem0;
    p.b_ih = b_ih; p.b_hh = b_hh;
    p.rk_W = rk_W; p.rk_b = rk_b; p.rb_W = rb_W; p.rb_b = rb_b;
    p.rg_W = rg_W; p.rg_b = rg_b; p.rs_W = rs_W; p.rs_b = rs_b;
    p.rgm_W = rgm_W; p.rgm_b = rgm_b;
    p.wk_W = wk_W; p.wk_b = wk_b; p.wb_W = wb_W; p.wb_b = wb_b;
    p.wg_W = wg_W; p.wg_b = wg_b; p.ws_W = ws_W; p.ws_b = ws_b;
    p.wgm_W = wgm_W; p.wgm_b = wgm_b;
    p.er_W = er_W; p.er_b = er_b; p.ad_W = ad_W; p.ad_b = ad_b;
    p.out_b = out_b; p.out = out;

    const size_t nWih  = (size_t)ZD * G4;
    const size_t nWhh  = (size_t)HCC * G4;
    const size_t nWout = (size_t)512 * OUTD;
    const size_t needT = (nWih + nWhh + nWout) * sizeof(float);
    float* ws = (float*)d_ws;

    if (ws_size >= needT) {
      dim3 blk(32, 8);
      transpose_k<<<dim3(ZD / 32, G4 / 32), blk, 0, stream>>>(w_ih, ws, G4, ZD);
      transpose_k<<<dim3(HCC / 32, G4 / 32), blk, 0, stream>>>(w_hh, ws + nWih, G4, HCC);
      transpose_k<<<dim3(512 / 32, OUTD / 32), blk, 0, stream>>>(out_W, ws + nWih + nWhh, OUTD, 512);
      p.wih = ws;                p.wih_sI = 1;   p.wih_sK = G4;
      p.whh = ws + nWih;         p.whh_sI = 1;   p.whh_sK = G4;
      p.outW = ws + nWih + nWhh; p.outW_sK = OUTD; p.outW_sO = 1;
    } else {
      p.wih = w_ih;  p.wih_sI = ZD;  p.wih_sK = 1;
      p.whh = w_hh;  p.whh_sI = HCC; p.whh_sK = 1;
      p.outW = out_W; p.outW_sK = 1; p.outW_sO = 512;
    }
    ntm_generic<<<dim3(BB), dim3(1024), 0, stream>>>(p);
  }
}